// Round 1
// baseline (927.786 us; speedup 1.0000x reference)
//
#include <hip/hip_runtime.h>

constexpr int B_ = 2;
constexpr int C_ = 64;      // input channels
constexpr int N_ = 40000;
constexpr int K_ = 6;
constexpr int S_ = B_ * N_ * K_;   // 480000 BN samples
constexpr float EPS_ = 1e-5f;
constexpr float INV_S = 1.0f / (float)S_;

// ws layout (floats):
//   V[B][N][128]  (c<64: dot(W0[c,0:64],x) ; c>=64: dot(W0[c-64,64:128],x))
//   stats[512]: sum0[64] sq0[64] sum1[64] sq1[64] sum2[128] sq2[128]
//   neg2[64]: -sum_j W0[c][64+j]  (pad-neighbor contribution)
constexpr int WS_STATS = B_ * N_ * 128;   // 10,240,000
constexpr int WS_NEG2  = WS_STATS + 512;

__global__ __launch_bounds__(256) void zero_stats_kernel(float* __restrict__ stats) {
    int t = blockIdx.x * 256 + threadIdx.x;
    if (t < 512) stats[t] = 0.f;
}

// ---------------- P0: V = M @ x  per (b,n);  M is 128x64 repack of W0 ----------------
__global__ __launch_bounds__(256) void p0_kernel(const float* __restrict__ pts,
                                                 const float* __restrict__ W0,
                                                 float* __restrict__ V,
                                                 float* __restrict__ neg2) {
    __shared__ float xs[64 * 68];    // [n_local][j], padded row 68
    __shared__ float Ms[128 * 64];   // [c][j], broadcast-read
    const int t  = threadIdx.x;
    const int b  = blockIdx.y;
    const int n0 = blockIdx.x * 64;

    #pragma unroll
    for (int i = 0; i < 32; ++i) {            // load M (repacked W0)
        int lin = t + 256 * i;                // 0..8191
        int c = lin >> 6, j = lin & 63;
        float v = (c < 64) ? W0[c * 128 + j] : W0[(c - 64) * 128 + 64 + j];
        Ms[lin] = v;
    }
    {
        int nl = t & 63, jr = t >> 6;
        #pragma unroll
        for (int jj = 0; jj < 16; ++jj) {     // load x tile (coalesced along n)
            int j = jj * 4 + jr;
            xs[nl * 68 + j] = pts[b * C_ * N_ + j * N_ + n0 + nl];
        }
    }
    __syncthreads();

    const int nl = t & 63, cg = t >> 6;       // wave-uniform cg
    const float4* xs4 = (const float4*)(xs + nl * 68);
    float* Vout = V + (b * N_ + n0 + nl) * 128 + cg * 32;

    #pragma unroll
    for (int c8 = 0; c8 < 8; ++c8) {
        int c0 = cg * 32 + c8 * 4;
        const float4* m0 = (const float4*)(Ms + (c0 + 0) * 64);
        const float4* m1 = (const float4*)(Ms + (c0 + 1) * 64);
        const float4* m2 = (const float4*)(Ms + (c0 + 2) * 64);
        const float4* m3 = (const float4*)(Ms + (c0 + 3) * 64);
        float4 a0 = {0,0,0,0}, a1 = {0,0,0,0}, a2 = {0,0,0,0}, a3 = {0,0,0,0};
        #pragma unroll
        for (int jj = 0; jj < 16; ++jj) {
            float4 xv = xs4[jj];
            float4 w0v = m0[jj], w1v = m1[jj], w2v = m2[jj], w3v = m3[jj];
            a0.x += w0v.x * xv.x; a0.y += w0v.y * xv.y; a0.z += w0v.z * xv.z; a0.w += w0v.w * xv.w;
            a1.x += w1v.x * xv.x; a1.y += w1v.y * xv.y; a1.z += w1v.z * xv.z; a1.w += w1v.w * xv.w;
            a2.x += w2v.x * xv.x; a2.y += w2v.y * xv.y; a2.z += w2v.z * xv.z; a2.w += w2v.w * xv.w;
            a3.x += w3v.x * xv.x; a3.y += w3v.y * xv.y; a3.z += w3v.z * xv.z; a3.w += w3v.w * xv.w;
        }
        float4 o;
        o.x = (a0.x + a0.y) + (a0.z + a0.w);
        o.y = (a1.x + a1.y) + (a1.z + a1.w);
        o.z = (a2.x + a2.y) + (a2.z + a2.w);
        o.w = (a3.x + a3.y) + (a3.z + a3.w);
        *(float4*)(Vout + c8 * 4) = o;
    }
    if (blockIdx.x == 0 && b == 0 && t < 64) {   // neg2 once
        float s = 0.f;
        for (int j = 0; j < 64; ++j) s += Ms[(64 + t) * 64 + j];
        neg2[t] = -s;
    }
}

// ---------------- P1: stats of z0 (bias dropped) ----------------
__global__ __launch_bounds__(256) void p1_kernel(const float* __restrict__ V,
                                                 const int* __restrict__ nidx,
                                                 const float* __restrict__ neg2,
                                                 float* __restrict__ stats) {
    const int lane = threadIdx.x & 63;
    const int w    = threadIdx.x >> 6;
    const int b    = blockIdx.y;
    const int n0   = blockIdx.x * 16;   // 96 samples/block
    const float ng = neg2[lane];
    float sum = 0.f, sq = 0.f;
    #pragma unroll 4
    for (int si = 0; si < 24; ++si) {
        int s = w * 24 + si;
        int n = n0 + s / 6;
        int m = nidx[n * 6 + (s % 6)];
        float v1 = V[(b * N_ + n) * 128 + lane];
        float v2 = (m < N_) ? V[(b * N_ + m) * 128 + 64 + lane] : ng;
        float z = v1 + v2;
        sum += z; sq += z * z;
    }
    __shared__ float red[2][4][64];
    red[0][w][lane] = sum;
    red[1][w][lane] = sq;
    __syncthreads();
    if (threadIdx.x < 64) {
        float s0 = (red[0][0][lane] + red[0][1][lane]) + (red[0][2][lane] + red[0][3][lane]);
        float q0 = (red[1][0][lane] + red[1][1][lane]) + (red[1][2][lane] + red[1][3][lane]);
        atomicAdd(&stats[lane], s0);
        atomicAdd(&stats[64 + lane], q0);
    }
}

// ---------------- P2: f0 -> z1 = W1@f0, stats1 ----------------
__global__ __launch_bounds__(256) void p2_kernel(const float* __restrict__ V,
                                                 const int* __restrict__ nidx,
                                                 const float* __restrict__ neg2,
                                                 const float* __restrict__ W1,
                                                 const float* __restrict__ g0,
                                                 const float* __restrict__ beta0,
                                                 float* __restrict__ stats) {
    __shared__ float f0s[48 * 68];
    __shared__ float w1s[64 * 68];
    const int t = threadIdx.x;
    const int lane = t & 63, w = t >> 6;
    const int b  = blockIdx.y;
    const int n0 = blockIdx.x * 8;      // 48 samples/block
    #pragma unroll
    for (int i = 0; i < 16; ++i) {
        int lin = t + 256 * i;
        w1s[(lin >> 6) * 68 + (lin & 63)] = W1[lin];
    }
    const float ng  = neg2[lane];
    const float mu0 = stats[lane] * INV_S;
    const float vr0 = stats[64 + lane] * INV_S - mu0 * mu0;
    const float a0  = rsqrtf(vr0 + EPS_) * g0[lane];
    const float d0  = beta0[lane] - mu0 * a0;
    #pragma unroll
    for (int si = 0; si < 12; ++si) {
        int s = w * 12 + si;
        int n = n0 + s / 6;
        int m = nidx[n * 6 + (s % 6)];
        float v1 = V[(b * N_ + n) * 128 + lane];
        float v2 = (m < N_) ? V[(b * N_ + m) * 128 + 64 + lane] : ng;
        float z = v1 + v2;
        f0s[s * 68 + lane] = fmaxf(z * a0 + d0, 0.f);
    }
    __syncthreads();
    float zsum = 0.f, zsq = 0.f;
    const float4* wrow = (const float4*)(w1s + lane * 68);
    #pragma unroll
    for (int gr = 0; gr < 3; ++gr) {
        int sb = w * 12 + gr * 4;
        float4 a[4] = {{0,0,0,0},{0,0,0,0},{0,0,0,0},{0,0,0,0}};
        #pragma unroll
        for (int jj = 0; jj < 16; ++jj) {
            float4 wv = wrow[jj];
            #pragma unroll
            for (int si = 0; si < 4; ++si) {
                const float4 fv = *(const float4*)(f0s + (sb + si) * 68 + jj * 4);
                a[si].x += wv.x * fv.x; a[si].y += wv.y * fv.y;
                a[si].z += wv.z * fv.z; a[si].w += wv.w * fv.w;
            }
        }
        #pragma unroll
        for (int si = 0; si < 4; ++si) {
            float z = (a[si].x + a[si].y) + (a[si].z + a[si].w);
            zsum += z; zsq += z * z;
        }
    }
    __shared__ float red[2][4][64];
    red[0][w][lane] = zsum;
    red[1][w][lane] = zsq;
    __syncthreads();
    if (t < 64) {
        float s1 = (red[0][0][lane] + red[0][1][lane]) + (red[0][2][lane] + red[0][3][lane]);
        float q1 = (red[1][0][lane] + red[1][1][lane]) + (red[1][2][lane] + red[1][3][lane]);
        atomicAdd(&stats[128 + lane], s1);
        atomicAdd(&stats[192 + lane], q1);
    }
}

// ---------------- P3: f0 -> f1 -> z2 = W2@f1, stats2, raw sign-max over k ----------------
__global__ __launch_bounds__(256) void p3_kernel(const float* __restrict__ V,
                                                 const int* __restrict__ nidx,
                                                 const float* __restrict__ neg2,
                                                 const float* __restrict__ W1,
                                                 const float* __restrict__ W2,
                                                 const float* __restrict__ g0, const float* __restrict__ beta0,
                                                 const float* __restrict__ g1, const float* __restrict__ beta1,
                                                 const float* __restrict__ g2,
                                                 float* __restrict__ stats,
                                                 float* __restrict__ outbuf) {
    __shared__ float fs[48 * 68];      // f0, then f1 (same rows reused)
    __shared__ float wbuf[128 * 68];   // W1 (64 rows) then W2 (128 rows)
    __shared__ float red[2][256];
    const int t = threadIdx.x;
    const int lane = t & 63, w = t >> 6;
    const int b  = blockIdx.y;
    const int n0 = blockIdx.x * 8;
    #pragma unroll
    for (int i = 0; i < 16; ++i) {
        int lin = t + 256 * i;
        wbuf[(lin >> 6) * 68 + (lin & 63)] = W1[lin];
    }
    const float ng  = neg2[lane];
    float mu0 = stats[lane] * INV_S;
    float vr0 = stats[64 + lane] * INV_S - mu0 * mu0;
    const float a0 = rsqrtf(vr0 + EPS_) * g0[lane];
    const float d0 = beta0[lane] - mu0 * a0;
    float mu1 = stats[128 + lane] * INV_S;
    float vr1 = stats[192 + lane] * INV_S - mu1 * mu1;
    const float a1 = rsqrtf(vr1 + EPS_) * g1[lane];
    const float d1 = beta1[lane] - mu1 * a1;
    #pragma unroll
    for (int si = 0; si < 12; ++si) {       // phase A: f0
        int s = w * 12 + si;
        int n = n0 + s / 6;
        int m = nidx[n * 6 + (s % 6)];
        float v1 = V[(b * N_ + n) * 128 + lane];
        float v2 = (m < N_) ? V[(b * N_ + m) * 128 + 64 + lane] : ng;
        float z = v1 + v2;
        fs[s * 68 + lane] = fmaxf(z * a0 + d0, 0.f);
    }
    __syncthreads();
    float f1v[12];                           // phase B: z1 -> f1 (regs)
    {
        const float4* wrow = (const float4*)(wbuf + lane * 68);
        #pragma unroll
        for (int gr = 0; gr < 3; ++gr) {
            int sb = w * 12 + gr * 4;
            float4 a[4] = {{0,0,0,0},{0,0,0,0},{0,0,0,0},{0,0,0,0}};
            #pragma unroll
            for (int jj = 0; jj < 16; ++jj) {
                float4 wv = wrow[jj];
                #pragma unroll
                for (int si = 0; si < 4; ++si) {
                    const float4 fv = *(const float4*)(fs + (sb + si) * 68 + jj * 4);
                    a[si].x += wv.x * fv.x; a[si].y += wv.y * fv.y;
                    a[si].z += wv.z * fv.z; a[si].w += wv.w * fv.w;
                }
            }
            #pragma unroll
            for (int si = 0; si < 4; ++si) {
                float z = (a[si].x + a[si].y) + (a[si].z + a[si].w);
                f1v[gr * 4 + si] = fmaxf(z * a1 + d1, 0.f);
            }
        }
    }
    __syncthreads();                         // all fs/wbuf reads done
    #pragma unroll
    for (int si = 0; si < 12; ++si) fs[(w * 12 + si) * 68 + lane] = f1v[si];
    #pragma unroll
    for (int i = 0; i < 32; ++i) {           // load W2 over W1
        int lin = t + 256 * i;
        wbuf[(lin >> 6) * 68 + (lin & 63)] = W2[lin];
    }
    __syncthreads();
    // phase C: z2 = W2 @ f1
    const int c2 = t & 127, sg = t >> 7;     // 2 sample-groups x 24 samples
    const bool pos = (g2[c2] >= 0.f);
    float zsum = 0.f, zsq = 0.f;
    float vals[4];
    #pragma unroll
    for (int i = 0; i < 4; ++i) vals[i] = pos ? -3.402823466e+38f : 3.402823466e+38f;
    const float4* w2row = (const float4*)(wbuf + c2 * 68);
    #pragma unroll
    for (int h = 0; h < 6; ++h) {
        int sb = sg * 24 + h * 4;
        float4 a[4] = {{0,0,0,0},{0,0,0,0},{0,0,0,0},{0,0,0,0}};
        #pragma unroll
        for (int jj = 0; jj < 16; ++jj) {
            float4 wv = w2row[jj];
            #pragma unroll
            for (int si = 0; si < 4; ++si) {
                const float4 fv = *(const float4*)(fs + (sb + si) * 68 + jj * 4);
                a[si].x += wv.x * fv.x; a[si].y += wv.y * fv.y;
                a[si].z += wv.z * fv.z; a[si].w += wv.w * fv.w;
            }
        }
        #pragma unroll
        for (int si = 0; si < 4; ++si) {
            float z = (a[si].x + a[si].y) + (a[si].z + a[si].w);
            zsum += z; zsq += z * z;
            int nloc = (h * 4 + si) / 6;     // compile-time after unroll
            vals[nloc] = pos ? fmaxf(vals[nloc], z) : fminf(vals[nloc], z);
        }
    }
    red[0][t] = zsum; red[1][t] = zsq;
    const int OF = B_ * N_;
    #pragma unroll
    for (int i = 0; i < 4; ++i) {            // raw sign-max -> d_out [b][c2][n]
        int n = n0 + sg * 4 + i;
        outbuf[OF + (b * 128 + c2) * N_ + n] = vals[i];
    }
    __syncthreads();
    if (t < 128) {
        atomicAdd(&stats[256 + t], red[0][t] + red[0][t + 128]);
        atomicAdd(&stats[384 + t], red[1][t] + red[1][t + 128]);
    }
}

// ---------------- P4: normalize new_feature in place + channel max ----------------
__global__ __launch_bounds__(256) void p4_kernel(const float* __restrict__ g2,
                                                 const float* __restrict__ beta2,
                                                 const float* __restrict__ stats,
                                                 float* __restrict__ outbuf) {
    __shared__ float a2s[128], d2s[128];
    const int t = threadIdx.x;
    if (t < 128) {
        float mu = stats[256 + t] * INV_S;
        float vr = stats[384 + t] * INV_S - mu * mu;
        float a = rsqrtf(vr + EPS_) * g2[t];
        a2s[t] = a;
        d2s[t] = beta2[t] - mu * a;
    }
    __syncthreads();
    const int b = blockIdx.y;
    const int n = blockIdx.x * 256 + t;
    if (n >= N_) return;
    const int OF = B_ * N_;
    float vmax = -3.402823466e+38f;
    #pragma unroll 8
    for (int c2 = 0; c2 < 128; ++c2) {
        int idx = OF + (b * 128 + c2) * N_ + n;
        float v = fmaxf(outbuf[idx] * a2s[c2] + d2s[c2], 0.f);
        outbuf[idx] = v;
        vmax = fmaxf(vmax, v);
    }
    outbuf[b * N_ + n] = vmax;
}

extern "C" void kernel_launch(void* const* d_in, const int* in_sizes, int n_in,
                              void* d_out, int out_size, void* d_ws, size_t ws_size,
                              hipStream_t stream) {
    (void)in_sizes; (void)n_in; (void)out_size; (void)ws_size;
    const float* pts   = (const float*)d_in[0];
    const int*   nidx  = (const int*)d_in[1];
    const float* W0    = (const float*)d_in[2];
    const float* g0    = (const float*)d_in[4];
    const float* beta0 = (const float*)d_in[5];
    const float* W1    = (const float*)d_in[6];
    const float* g1    = (const float*)d_in[8];
    const float* beta1 = (const float*)d_in[9];
    const float* W2    = (const float*)d_in[10];
    const float* g2    = (const float*)d_in[12];
    const float* beta2 = (const float*)d_in[13];
    float* ws    = (float*)d_ws;
    float* V     = ws;
    float* stats = ws + WS_STATS;
    float* neg2  = ws + WS_NEG2;
    float* out   = (float*)d_out;

    hipLaunchKernelGGL(zero_stats_kernel, dim3(2), dim3(256), 0, stream, stats);
    hipLaunchKernelGGL(p0_kernel, dim3(N_ / 64, B_), dim3(256), 0, stream, pts, W0, V, neg2);
    hipLaunchKernelGGL(p1_kernel, dim3(N_ / 16, B_), dim3(256), 0, stream, V, nidx, neg2, stats);
    hipLaunchKernelGGL(p2_kernel, dim3(N_ / 8, B_), dim3(256), 0, stream, V, nidx, neg2, W1, g0, beta0, stats);
    hipLaunchKernelGGL(p3_kernel, dim3(N_ / 8, B_), dim3(256), 0, stream, V, nidx, neg2, W1, W2,
                       g0, beta0, g1, beta1, g2, stats, out);
    hipLaunchKernelGGL(p4_kernel, dim3((N_ + 255) / 256, B_), dim3(256), 0, stream, g2, beta2, stats, out);
}

// Round 3
// 475.939 us; speedup vs baseline: 1.9494x; 1.9494x over previous
//
#include <hip/hip_runtime.h>

typedef unsigned short u16;
typedef unsigned int uint;
typedef short bf16x8 __attribute__((ext_vector_type(8)));
typedef float f32x4 __attribute__((ext_vector_type(4)));

constexpr int B_ = 2;
constexpr int N_ = 40000;
constexpr int SPB = 240000;            // samples per batch = N*6
constexpr int S_ = B_ * SPB;           // 480000 BN samples
constexpr float EPS_ = 1e-5f;
constexpr float INV_S = 1.0f / (float)S_;
constexpr int OF_ = B_ * N_;           // out_feature elems before new_feature

// ws layout: V bf16 [B*N][128] = 10,240,000 u16 (= 5,120,000 floats)
//            stats[512] f32, neg2[64] f32
constexpr int WS_V_U16   = B_ * N_ * 128;
constexpr int WS_STATS_F = WS_V_U16 / 2;
constexpr int WS_NEG2_F  = WS_STATS_F + 512;

// ---------- helpers ----------
__device__ inline float b2f_lo(uint u) { return __builtin_bit_cast(float, u << 16); }
__device__ inline float b2f_hi(uint u) { return __builtin_bit_cast(float, u & 0xffff0000u); }
__device__ inline float b2fu(u16 s)    { return __builtin_bit_cast(float, ((uint)s) << 16); }
__device__ inline u16 f2b(float f) {   // RNE float->bf16
    uint b = __builtin_bit_cast(uint, f);
    return (u16)((b + 0x7fffu + ((b >> 16) & 1u)) >> 16);
}
__device__ inline void unp8(uint4 q, float* f) {
    f[0] = b2f_lo(q.x); f[1] = b2f_hi(q.x); f[2] = b2f_lo(q.y); f[3] = b2f_hi(q.y);
    f[4] = b2f_lo(q.z); f[5] = b2f_hi(q.z); f[6] = b2f_lo(q.w); f[7] = b2f_hi(q.w);
}
// monotone float<->uint map for atomicMax-based float max
__device__ inline uint fmap(float f) {
    int i = __float_as_int(f);
    return (i >= 0) ? ((uint)i | 0x80000000u) : ~(uint)i;
}
__device__ inline float funmap(uint u) {
    int i = (u & 0x80000000u) ? (int)(u & 0x7fffffffu) : (int)~u;
    return __int_as_float(i);
}

__global__ __launch_bounds__(256) void zero_stats_kernel(float* __restrict__ stats) {
    int t = blockIdx.x * 256 + threadIdx.x;
    if (t < 512) stats[t] = 0.f;
}

// ---------------- P0: V = M @ x per (b,n); M is 128x64 repack of W0; V stored bf16 ----------------
__global__ __launch_bounds__(256) void p0_kernel(const float* __restrict__ pts,
                                                 const float* __restrict__ W0,
                                                 u16* __restrict__ V,
                                                 float* __restrict__ neg2) {
    __shared__ float xs[64 * 68];
    __shared__ float Ms[128 * 64];
    const int t  = threadIdx.x;
    const int b  = blockIdx.y;
    const int n0 = blockIdx.x * 64;

    #pragma unroll
    for (int i = 0; i < 32; ++i) {
        int lin = t + 256 * i;
        int c = lin >> 6, j = lin & 63;
        Ms[lin] = (c < 64) ? W0[c * 128 + j] : W0[(c - 64) * 128 + 64 + j];
    }
    {
        int nl = t & 63, jr = t >> 6;
        #pragma unroll
        for (int jj = 0; jj < 16; ++jj) {
            int j = jj * 4 + jr;
            xs[nl * 68 + j] = pts[b * 64 * N_ + j * N_ + n0 + nl];
        }
    }
    __syncthreads();

    const int nl = t & 63, cg = t >> 6;
    const float4* xs4 = (const float4*)(xs + nl * 68);
    u16* Vout = V + (size_t)(b * N_ + n0 + nl) * 128 + cg * 32;

    #pragma unroll
    for (int c8 = 0; c8 < 8; ++c8) {
        int c0 = cg * 32 + c8 * 4;
        const float4* m0 = (const float4*)(Ms + (c0 + 0) * 64);
        const float4* m1 = (const float4*)(Ms + (c0 + 1) * 64);
        const float4* m2 = (const float4*)(Ms + (c0 + 2) * 64);
        const float4* m3 = (const float4*)(Ms + (c0 + 3) * 64);
        float4 a0 = {0,0,0,0}, a1 = {0,0,0,0}, a2 = {0,0,0,0}, a3 = {0,0,0,0};
        #pragma unroll
        for (int jj = 0; jj < 16; ++jj) {
            float4 xv = xs4[jj];
            float4 w0v = m0[jj], w1v = m1[jj], w2v = m2[jj], w3v = m3[jj];
            a0.x += w0v.x * xv.x; a0.y += w0v.y * xv.y; a0.z += w0v.z * xv.z; a0.w += w0v.w * xv.w;
            a1.x += w1v.x * xv.x; a1.y += w1v.y * xv.y; a1.z += w1v.z * xv.z; a1.w += w1v.w * xv.w;
            a2.x += w2v.x * xv.x; a2.y += w2v.y * xv.y; a2.z += w2v.z * xv.z; a2.w += w2v.w * xv.w;
            a3.x += w3v.x * xv.x; a3.y += w3v.y * xv.y; a3.z += w3v.z * xv.z; a3.w += w3v.w * xv.w;
        }
        ushort4 o;
        o.x = f2b((a0.x + a0.y) + (a0.z + a0.w));
        o.y = f2b((a1.x + a1.y) + (a1.z + a1.w));
        o.z = f2b((a2.x + a2.y) + (a2.z + a2.w));
        o.w = f2b((a3.x + a3.y) + (a3.z + a3.w));
        *(ushort4*)(Vout + c8 * 4) = o;
    }
    if (blockIdx.x == 0 && b == 0 && t < 64) {
        float s = 0.f;
        for (int j = 0; j < 64; ++j) s += Ms[(64 + t) * 64 + j];
        neg2[t] = -s;
    }
}

// ---------------- P1: stats of z0 (gather only, no store) ----------------
__global__ __launch_bounds__(256) void p1_kernel(const u16* __restrict__ V,
                                                 const int* __restrict__ nidx,
                                                 const float* __restrict__ neg2,
                                                 float* __restrict__ stats) {
    const int t = threadIdx.x;
    const int c = t & 63, sg = t >> 6;
    const int b = blockIdx.y;
    const int n0 = blockIdx.x * 32;
    const float ng = neg2[c];
    float sum = 0.f, sq = 0.f;
    for (int i = 0; i < 8; ++i) {
        int n = n0 + sg * 8 + i;
        float v1 = b2fu(V[(size_t)(b * N_ + n) * 128 + c]);
        #pragma unroll
        for (int k = 0; k < 6; ++k) {
            int m = nidx[n * 6 + k];
            float v2 = (m < N_) ? b2fu(V[(size_t)(b * N_ + m) * 128 + 64 + c]) : ng;
            float z = v1 + v2;
            sum += z; sq += z * z;
        }
    }
    __shared__ float red[2][4][64];
    red[0][sg][c] = sum;
    red[1][sg][c] = sq;
    __syncthreads();
    if (t < 64) {
        float s0 = (red[0][0][t] + red[0][1][t]) + (red[0][2][t] + red[0][3][t]);
        float q0 = (red[1][0][t] + red[1][1][t]) + (red[1][2][t] + red[1][3][t]);
        atomicAdd(&stats[t], s0);
        atomicAdd(&stats[64 + t], q0);
    }
}

// build A-frag: f0 = relu(a0*(v1+v2)+d0) for 8 channels starting at j0, packed bf16
__device__ inline bf16x8 build_af(const u16* __restrict__ V, int row1, int row2,
                                  const float* adt0, const float* adt1,
                                  const float* ngs, int j0) {
    float v1f[8], v2f[8];
    uint4 q1 = *(const uint4*)(V + (size_t)row1 * 128 + j0);
    unp8(q1, v1f);
    if (row2 >= 0) {
        uint4 q2 = *(const uint4*)(V + (size_t)row2 * 128 + 64 + j0);
        unp8(q2, v2f);
    } else {
        #pragma unroll
        for (int i = 0; i < 8; ++i) v2f[i] = ngs[j0 + i];
    }
    bf16x8 r;
    #pragma unroll
    for (int i = 0; i < 8; ++i) {
        float f0 = fmaxf((v1f[i] + v2f[i]) * adt0[j0 + i] + adt1[j0 + i], 0.f);
        r[i] = (short)f2b(f0);
    }
    return r;
}

// ---------------- P2: f0 -> z1 = f0 @ W1^T (MFMA), stats1 only ----------------
__global__ __launch_bounds__(256) void p2_kernel(const u16* __restrict__ V,
                                                 const int* __restrict__ nidx,
                                                 const float* __restrict__ neg2,
                                                 const float* __restrict__ W1,
                                                 const float* __restrict__ g0,
                                                 const float* __restrict__ beta0,
                                                 float* __restrict__ stats) {
    __shared__ float adt0[64], adt1[64], ngs[64];
    __shared__ float red[2][4][64];
    const int t = threadIdx.x, lane = t & 63, w = t >> 6;
    const int cb = lane & 15, kq = lane >> 4;
    if (t < 64) {
        float mu = stats[t] * INV_S, vr = stats[64 + t] * INV_S - mu * mu;
        float a = rsqrtf(vr + EPS_) * g0[t];
        adt0[t] = a; adt1[t] = beta0[t] - mu * a; ngs[t] = neg2[t];
    }
    __syncthreads();
    const int b = blockIdx.y;
    const int slb = blockIdx.x * 192 + w * 48;

    bf16x8 bf[4][2];
    #pragma unroll
    for (int ct = 0; ct < 4; ++ct)
        #pragma unroll
        for (int kk = 0; kk < 2; ++kk) {
            const float* wp = W1 + (ct * 16 + cb) * 64 + kk * 32 + kq * 8;
            #pragma unroll
            for (int i = 0; i < 8; ++i) bf[ct][kk][i] = (short)f2b(wp[i]);
        }

    f32x4 acc[3][4] = {};
    #pragma unroll
    for (int mt = 0; mt < 3; ++mt) {
        int sl = slb + mt * 16 + cb;
        int n = sl / 6;
        int m = nidx[sl];
        int row1 = b * N_ + n;
        int row2 = (m < N_) ? (b * N_ + m) : -1;
        bf16x8 af[2];
        #pragma unroll
        for (int kk = 0; kk < 2; ++kk)
            af[kk] = build_af(V, row1, row2, adt0, adt1, ngs, kk * 32 + kq * 8);
        #pragma unroll
        for (int ct = 0; ct < 4; ++ct) {
            acc[mt][ct] = __builtin_amdgcn_mfma_f32_16x16x32_bf16(af[0], bf[ct][0], acc[mt][ct], 0, 0, 0);
            acc[mt][ct] = __builtin_amdgcn_mfma_f32_16x16x32_bf16(af[1], bf[ct][1], acc[mt][ct], 0, 0, 0);
        }
    }
    float ssum[4] = {0,0,0,0}, ssq[4] = {0,0,0,0};
    #pragma unroll
    for (int mt = 0; mt < 3; ++mt)
        #pragma unroll
        for (int ct = 0; ct < 4; ++ct)
            #pragma unroll
            for (int r = 0; r < 4; ++r) {
                float z = acc[mt][ct][r];
                ssum[ct] += z; ssq[ct] += z * z;
            }
    #pragma unroll
    for (int ct = 0; ct < 4; ++ct) {
        ssum[ct] += __shfl_xor(ssum[ct], 16); ssum[ct] += __shfl_xor(ssum[ct], 32);
        ssq[ct]  += __shfl_xor(ssq[ct], 16);  ssq[ct]  += __shfl_xor(ssq[ct], 32);
    }
    if (lane < 16) {
        #pragma unroll
        for (int ct = 0; ct < 4; ++ct) {
            red[0][w][ct * 16 + lane] = ssum[ct];
            red[1][w][ct * 16 + lane] = ssq[ct];
        }
    }
    __syncthreads();
    if (t < 64) {
        float s = (red[0][0][t] + red[0][1][t]) + (red[0][2][t] + red[0][3][t]);
        float q = (red[1][0][t] + red[1][1][t]) + (red[1][2][t] + red[1][3][t]);
        atomicAdd(&stats[128 + t], s);
        atomicAdd(&stats[192 + t], q);
    }
}

// ---------------- P3: f0 -> z1 -> f1 -> z2 (MFMA x2), stats2, sign-max over k ----------------
__global__ __launch_bounds__(256) void p3_kernel(const u16* __restrict__ V,
                                                 const int* __restrict__ nidx,
                                                 const float* __restrict__ neg2,
                                                 const float* __restrict__ W1,
                                                 const float* __restrict__ W2,
                                                 const float* __restrict__ g0, const float* __restrict__ beta0,
                                                 const float* __restrict__ g1, const float* __restrict__ beta1,
                                                 const float* __restrict__ g2,
                                                 float* __restrict__ stats,
                                                 float* __restrict__ out) {
    __shared__ u16  f1s[4][3072];            // per-wave 48x64 bf16, XOR-swizzled
    __shared__ uint bmax[32][128];           // per-block sign-adjusted max (fmap'd)
    __shared__ float adt0[64], adt1[64], adt2[64], adt3[64], ngs[64];
    __shared__ float psign[128];
    __shared__ float red[2][4][128];
    const int t = threadIdx.x, lane = t & 63, w = t >> 6;
    const int cb = lane & 15, kq = lane >> 4;
    if (t < 64) {
        float mu0 = stats[t] * INV_S, vr0 = stats[64 + t] * INV_S - mu0 * mu0;
        float a0 = rsqrtf(vr0 + EPS_) * g0[t];
        adt0[t] = a0; adt1[t] = beta0[t] - mu0 * a0;
        float mu1 = stats[128 + t] * INV_S, vr1 = stats[192 + t] * INV_S - mu1 * mu1;
        float a1 = rsqrtf(vr1 + EPS_) * g1[t];
        adt2[t] = a1; adt3[t] = beta1[t] - mu1 * a1;
        ngs[t] = neg2[t];
    }
    if (t < 128) psign[t] = (g2[t] >= 0.f) ? 1.f : -1.f;
    #pragma unroll
    for (int i = 0; i < 16; ++i) ((uint*)bmax)[t + 256 * i] = 0u;
    __syncthreads();

    const int b = blockIdx.y;
    const int slb = blockIdx.x * 192 + w * 48;

    // ---- front: z1 = f0 @ W1^T ----
    bf16x8 bf1[4][2];
    #pragma unroll
    for (int ct = 0; ct < 4; ++ct)
        #pragma unroll
        for (int kk = 0; kk < 2; ++kk) {
            const float* wp = W1 + (ct * 16 + cb) * 64 + kk * 32 + kq * 8;
            #pragma unroll
            for (int i = 0; i < 8; ++i) bf1[ct][kk][i] = (short)f2b(wp[i]);
        }
    f32x4 acc1[3][4] = {};
    #pragma unroll
    for (int mt = 0; mt < 3; ++mt) {
        int sl = slb + mt * 16 + cb;
        int n = sl / 6;
        int m = nidx[sl];
        int row1 = b * N_ + n;
        int row2 = (m < N_) ? (b * N_ + m) : -1;
        bf16x8 af[2];
        #pragma unroll
        for (int kk = 0; kk < 2; ++kk)
            af[kk] = build_af(V, row1, row2, adt0, adt1, ngs, kk * 32 + kq * 8);
        #pragma unroll
        for (int ct = 0; ct < 4; ++ct) {
            acc1[mt][ct] = __builtin_amdgcn_mfma_f32_16x16x32_bf16(af[0], bf1[ct][0], acc1[mt][ct], 0, 0, 0);
            acc1[mt][ct] = __builtin_amdgcn_mfma_f32_16x16x32_bf16(af[1], bf1[ct][1], acc1[mt][ct], 0, 0, 0);
        }
    }
    // ---- BN1 + ReLU -> f1 into wave-local LDS (XOR swizzle on 8-row stripes) ----
    u16* fb = f1s[w];
    #pragma unroll
    for (int mt = 0; mt < 3; ++mt)
        #pragma unroll
        for (int ct = 0; ct < 4; ++ct) {
            float a1c = adt2[ct * 16 + cb], d1c = adt3[ct * 16 + cb];
            #pragma unroll
            for (int r = 0; r < 4; ++r) {
                float f1 = fmaxf(acc1[mt][ct][r] * a1c + d1c, 0.f);
                int rl = mt * 16 + kq * 4 + r;
                fb[rl * 64 + ((ct * 16 + cb) ^ ((rl & 7) << 3))] = f2b(f1);
            }
        }
    // ---- back: z2 = f1 @ W2^T, two 64-col halves ----
    float ssum[8] = {0,0,0,0,0,0,0,0}, ssq[8] = {0,0,0,0,0,0,0,0};
    #pragma unroll
    for (int half = 0; half < 2; ++half) {
        bf16x8 bf2[4][2];
        #pragma unroll
        for (int ct = 0; ct < 4; ++ct)
            #pragma unroll
            for (int kk = 0; kk < 2; ++kk) {
                const float* wp = W2 + (half * 64 + ct * 16 + cb) * 64 + kk * 32 + kq * 8;
                #pragma unroll
                for (int i = 0; i < 8; ++i) bf2[ct][kk][i] = (short)f2b(wp[i]);
            }
        f32x4 acc2[3][4] = {};
        #pragma unroll
        for (int mt = 0; mt < 3; ++mt) {
            int rl = mt * 16 + cb;
            bf16x8 af2[2];
            #pragma unroll
            for (int kk = 0; kk < 2; ++kk) {
                int j0 = kk * 32 + kq * 8;
                uint4 q = *(const uint4*)(fb + rl * 64 + (j0 ^ ((rl & 7) << 3)));
                af2[kk] = __builtin_bit_cast(bf16x8, q);
            }
            #pragma unroll
            for (int ct = 0; ct < 4; ++ct) {
                acc2[mt][ct] = __builtin_amdgcn_mfma_f32_16x16x32_bf16(af2[0], bf2[ct][0], acc2[mt][ct], 0, 0, 0);
                acc2[mt][ct] = __builtin_amdgcn_mfma_f32_16x16x32_bf16(af2[1], bf2[ct][1], acc2[mt][ct], 0, 0, 0);
            }
        }
        #pragma unroll
        for (int ct = 0; ct < 4; ++ct) {
            int c2 = half * 64 + ct * 16 + cb;
            float ps = psign[c2];
            #pragma unroll
            for (int mt = 0; mt < 3; ++mt)
                #pragma unroll
                for (int r = 0; r < 4; ++r) {
                    float z = acc2[mt][ct][r];
                    ssum[half * 4 + ct] += z;
                    ssq[half * 4 + ct] += z * z;
                    int rl = mt * 16 + kq * 4 + r;
                    int nl = (w * 48 + rl) / 6;
                    atomicMax(&bmax[nl][c2], fmap(z * ps));
                }
        }
    }
    // ---- stats2 reduce ----
    #pragma unroll
    for (int j = 0; j < 8; ++j) {
        ssum[j] += __shfl_xor(ssum[j], 16); ssum[j] += __shfl_xor(ssum[j], 32);
        ssq[j]  += __shfl_xor(ssq[j], 16);  ssq[j]  += __shfl_xor(ssq[j], 32);
    }
    if (lane < 16) {
        #pragma unroll
        for (int j = 0; j < 8; ++j) {
            int c = (j >> 2) * 64 + (j & 3) * 16 + lane;
            red[0][w][c] = ssum[j];
            red[1][w][c] = ssq[j];
        }
    }
    __syncthreads();
    if (t < 128) {
        float s = (red[0][0][t] + red[0][1][t]) + (red[0][2][t] + red[0][3][t]);
        float q = (red[1][0][t] + red[1][1][t]) + (red[1][2][t] + red[1][3][t]);
        atomicAdd(&stats[256 + t], s);
        atomicAdd(&stats[384 + t], q);
    }
    // ---- write raw sign-max: out[b][c2][n0..n0+31] ----
    {
        int c2 = t >> 1, nh = t & 1;
        float ps = psign[c2];
        float* op = out + OF_ + ((size_t)b * 128 + c2) * N_ + blockIdx.x * 32 + nh * 16;
        #pragma unroll
        for (int i4 = 0; i4 < 4; ++i4) {
            float4 v;
            v.x = funmap(bmax[nh * 16 + i4 * 4 + 0][c2]) * ps;
            v.y = funmap(bmax[nh * 16 + i4 * 4 + 1][c2]) * ps;
            v.z = funmap(bmax[nh * 16 + i4 * 4 + 2][c2]) * ps;
            v.w = funmap(bmax[nh * 16 + i4 * 4 + 3][c2]) * ps;
            *(float4*)(op + i4 * 4) = v;
        }
    }
}

// ---------------- P4: normalize new_feature in place + channel max ----------------
__global__ __launch_bounds__(256) void p4_kernel(const float* __restrict__ g2,
                                                 const float* __restrict__ beta2,
                                                 const float* __restrict__ stats,
                                                 float* __restrict__ outbuf) {
    __shared__ float a2s[128], d2s[128];
    const int t = threadIdx.x;
    if (t < 128) {
        float mu = stats[256 + t] * INV_S;
        float vr = stats[384 + t] * INV_S - mu * mu;
        float a = rsqrtf(vr + EPS_) * g2[t];
        a2s[t] = a;
        d2s[t] = beta2[t] - mu * a;
    }
    __syncthreads();
    const int b = blockIdx.y;
    const int n = blockIdx.x * 256 + t;
    if (n >= N_) return;
    float vmax = -3.402823466e+38f;
    #pragma unroll 8
    for (int c2 = 0; c2 < 128; ++c2) {
        size_t idx = OF_ + ((size_t)b * 128 + c2) * N_ + n;
        float v = fmaxf(outbuf[idx] * a2s[c2] + d2s[c2], 0.f);
        outbuf[idx] = v;
        vmax = fmaxf(vmax, v);
    }
    outbuf[b * N_ + n] = vmax;
}

extern "C" void kernel_launch(void* const* d_in, const int* in_sizes, int n_in,
                              void* d_out, int out_size, void* d_ws, size_t ws_size,
                              hipStream_t stream) {
    (void)in_sizes; (void)n_in; (void)out_size; (void)ws_size;
    const float* pts   = (const float*)d_in[0];
    const int*   nidx  = (const int*)d_in[1];
    const float* W0    = (const float*)d_in[2];
    const float* g0    = (const float*)d_in[4];
    const float* beta0 = (const float*)d_in[5];
    const float* W1    = (const float*)d_in[6];
    const float* g1    = (const float*)d_in[8];
    const float* beta1 = (const float*)d_in[9];
    const float* W2    = (const float*)d_in[10];
    const float* g2    = (const float*)d_in[12];
    const float* beta2 = (const float*)d_in[13];
    u16*   V     = (u16*)d_ws;
    float* stats = (float*)d_ws + WS_STATS_F;
    float* neg2  = (float*)d_ws + WS_NEG2_F;
    float* out   = (float*)d_out;

    hipLaunchKernelGGL(zero_stats_kernel, dim3(2), dim3(256), 0, stream, stats);
    hipLaunchKernelGGL(p0_kernel, dim3(N_ / 64, B_), dim3(256), 0, stream, pts, W0, V, neg2);
    hipLaunchKernelGGL(p1_kernel, dim3(N_ / 32, B_), dim3(256), 0, stream, V, nidx, neg2, stats);
    hipLaunchKernelGGL(p2_kernel, dim3(SPB / 192, B_), dim3(256), 0, stream, V, nidx, neg2, W1, g0, beta0, stats);
    hipLaunchKernelGGL(p3_kernel, dim3(SPB / 192, B_), dim3(256), 0, stream, V, nidx, neg2, W1, W2,
                       g0, beta0, g1, beta1, g2, stats, out);
    hipLaunchKernelGGL(p4_kernel, dim3((N_ + 255) / 256, B_), dim3(256), 0, stream, g2, beta2, stats, out);
}

// Round 4
// 367.845 us; speedup vs baseline: 2.5222x; 1.2939x over previous
//
#include <hip/hip_runtime.h>

typedef unsigned short u16;
typedef unsigned int uint;
typedef short bf16x8 __attribute__((ext_vector_type(8)));
typedef float f32x4 __attribute__((ext_vector_type(4)));

constexpr int B_ = 2;
constexpr int N_ = 40000;
constexpr int SPB = 240000;            // samples per batch = N*6
constexpr int S_ = B_ * SPB;           // 480000 BN samples
constexpr float EPS_ = 1e-5f;
constexpr float INV_S = 1.0f / (float)S_;
constexpr int OF_ = B_ * N_;           // out_feature elems before new_feature

// ws layout:
//   V bf16 [B*N][128]                       u16[10,240,000]
//   stats[512] f32, neg2[64] f32
//   packed weights (bf16, fragment order):  Mpack[8192] W1p[4096] W2p[8192]
constexpr int WS_V_U16    = B_ * N_ * 128;
constexpr int WS_STATS_F  = WS_V_U16 / 2;
constexpr int WS_NEG2_F   = WS_STATS_F + 512;
constexpr int WS_PACK_U16 = WS_V_U16 + 2 * (512 + 64);   // u16 units, 16B-aligned
constexpr int MP_OFF  = 0;       // 8 ct * 2 kk * 64 lanes * 8
constexpr int W1P_OFF = 8192;    // 4 ct * 2 * 64 * 8
constexpr int W2P_OFF = 12288;   // 8 ct * 2 * 64 * 8

// ---------- helpers ----------
__device__ inline float b2f_lo(uint u) { return __builtin_bit_cast(float, u << 16); }
__device__ inline float b2f_hi(uint u) { return __builtin_bit_cast(float, u & 0xffff0000u); }
__device__ inline float b2fu(u16 s)    { return __builtin_bit_cast(float, ((uint)s) << 16); }
__device__ inline u16 f2b(float f) {   // RNE float->bf16
    uint b = __builtin_bit_cast(uint, f);
    return (u16)((b + 0x7fffu + ((b >> 16) & 1u)) >> 16);
}
__device__ inline void unp8(uint4 q, float* f) {
    f[0] = b2f_lo(q.x); f[1] = b2f_hi(q.x); f[2] = b2f_lo(q.y); f[3] = b2f_hi(q.y);
    f[4] = b2f_lo(q.z); f[5] = b2f_hi(q.z); f[6] = b2f_lo(q.w); f[7] = b2f_hi(q.w);
}
// monotone float<->uint map for atomicMax-based float max
__device__ inline uint fmap(float f) {
    int i = __float_as_int(f);
    return (i >= 0) ? ((uint)i | 0x80000000u) : ~(uint)i;
}
__device__ inline float funmap(uint u) {
    int i = (u & 0x80000000u) ? (int)(u & 0x7fffffffu) : (int)~u;
    return __int_as_float(i);
}

// ---------------- WPREP: zero stats, neg2, pack M/W1/W2 into fragment-ordered bf16 ----------------
// fragment group g = grp*64 + lane; value[i] = W[(ct*16 + (lane&15))*K + kk*32 + (lane>>4)*8 + i]
__global__ __launch_bounds__(256) void wprep_kernel(const float* __restrict__ W0,
                                                    const float* __restrict__ W1,
                                                    const float* __restrict__ W2,
                                                    float* __restrict__ stats,
                                                    float* __restrict__ neg2,
                                                    u16* __restrict__ pack) {
    const int t = threadIdx.x;
    stats[t] = 0.f; stats[t + 256] = 0.f;
    if (t < 64) {
        float s = 0.f;
        for (int j = 0; j < 64; ++j) s += W0[t * 128 + 64 + j];
        neg2[t] = -s;
    }
    // 40 groups of 64 lanes: 0..15 Mpack(ct 0..7, kk 0..1), 16..23 W1p, 24..39 W2p
    for (int g = t; g < 40 * 64; g += 256) {
        int lane = g & 63, grp = g >> 6;
        int cb = lane & 15, kq = lane >> 4;
        ushort4 lo, hi;
        u16* dst;
        if (grp < 16) {
            int ct = grp >> 1, kk = grp & 1;
            int c = ct * 16 + cb, jb = kk * 32 + kq * 8;
            dst = pack + MP_OFF + g * 8;
            float v[8];
            #pragma unroll
            for (int i = 0; i < 8; ++i)
                v[i] = (c < 64) ? W0[c * 128 + jb + i] : W0[(c - 64) * 128 + 64 + jb + i];
            lo = {f2b(v[0]), f2b(v[1]), f2b(v[2]), f2b(v[3])};
            hi = {f2b(v[4]), f2b(v[5]), f2b(v[6]), f2b(v[7])};
        } else if (grp < 24) {
            int g2 = grp - 16;
            int ct = g2 >> 1, kk = g2 & 1;
            const float* wp = W1 + (ct * 16 + cb) * 64 + kk * 32 + kq * 8;
            dst = pack + W1P_OFF + (g2 * 64 + lane) * 8;
            lo = {f2b(wp[0]), f2b(wp[1]), f2b(wp[2]), f2b(wp[3])};
            hi = {f2b(wp[4]), f2b(wp[5]), f2b(wp[6]), f2b(wp[7])};
        } else {
            int g3 = grp - 24;
            int ct = g3 >> 1, kk = g3 & 1;
            const float* wp = W2 + (ct * 16 + cb) * 64 + kk * 32 + kq * 8;
            dst = pack + W2P_OFF + (g3 * 64 + lane) * 8;
            lo = {f2b(wp[0]), f2b(wp[1]), f2b(wp[2]), f2b(wp[3])};
            hi = {f2b(wp[4]), f2b(wp[5]), f2b(wp[6]), f2b(wp[7])};
        }
        *(ushort4*)dst = lo;
        *(ushort4*)(dst + 4) = hi;
    }
}

// ---------------- P0 (MFMA): V[point][c] = M @ x, per wave 48 points x 128 channels ----------------
__global__ __launch_bounds__(256) void p0_kernel(const float* __restrict__ pts,
                                                 const u16* __restrict__ pack,
                                                 u16* __restrict__ V) {
    const int t = threadIdx.x, lane = t & 63, w = t >> 6;
    const int cb = lane & 15, kq = lane >> 4;
    const int b = blockIdx.y;
    const int n0 = blockIdx.x * 192 + w * 48;
    const uint4* mp = (const uint4*)(pack + MP_OFF);

    bf16x8 af[3][2];
    #pragma unroll
    for (int mt = 0; mt < 3; ++mt) {
        int n = n0 + mt * 16 + cb;
        int nc = (n < N_) ? n : (N_ - 1);
        const float* xp = pts + b * 64 * N_ + nc;
        #pragma unroll
        for (int kk = 0; kk < 2; ++kk) {
            int jb = kk * 32 + kq * 8;
            #pragma unroll
            for (int i = 0; i < 8; ++i)
                af[mt][kk][i] = (short)f2b(xp[(size_t)(jb + i) * N_]);
        }
    }
    #pragma unroll
    for (int ct = 0; ct < 8; ++ct) {
        bf16x8 b0 = __builtin_bit_cast(bf16x8, mp[(ct * 2 + 0) * 64 + lane]);
        bf16x8 b1 = __builtin_bit_cast(bf16x8, mp[(ct * 2 + 1) * 64 + lane]);
        #pragma unroll
        for (int mt = 0; mt < 3; ++mt) {
            f32x4 acc = {};
            acc = __builtin_amdgcn_mfma_f32_16x16x32_bf16(af[mt][0], b0, acc, 0, 0, 0);
            acc = __builtin_amdgcn_mfma_f32_16x16x32_bf16(af[mt][1], b1, acc, 0, 0, 0);
            int rbase = n0 + mt * 16 + kq * 4;
            #pragma unroll
            for (int r = 0; r < 4; ++r) {
                int n = rbase + r;
                if (n < N_) V[(size_t)(b * N_ + n) * 128 + ct * 16 + cb] = f2b(acc[r]);
            }
        }
    }
}

// ---------------- P1: stats of z0 (gather only, no store) ----------------
__global__ __launch_bounds__(256) void p1_kernel(const u16* __restrict__ V,
                                                 const int* __restrict__ nidx,
                                                 const float* __restrict__ neg2,
                                                 float* __restrict__ stats) {
    const int t = threadIdx.x;
    const int c = t & 63, sg = t >> 6;
    const int b = blockIdx.y;
    const int n0 = blockIdx.x * 32;
    const float ng = neg2[c];
    float sum = 0.f, sq = 0.f;
    for (int i = 0; i < 8; ++i) {
        int n = n0 + sg * 8 + i;
        float v1 = b2fu(V[(size_t)(b * N_ + n) * 128 + c]);
        #pragma unroll
        for (int k = 0; k < 6; ++k) {
            int m = nidx[n * 6 + k];
            float v2 = (m < N_) ? b2fu(V[(size_t)(b * N_ + m) * 128 + 64 + c]) : ng;
            float z = v1 + v2;
            sum += z; sq += z * z;
        }
    }
    __shared__ float red[2][4][64];
    red[0][sg][c] = sum;
    red[1][sg][c] = sq;
    __syncthreads();
    if (t < 64) {
        float s0 = (red[0][0][t] + red[0][1][t]) + (red[0][2][t] + red[0][3][t]);
        float q0 = (red[1][0][t] + red[1][1][t]) + (red[1][2][t] + red[1][3][t]);
        atomicAdd(&stats[t], s0);
        atomicAdd(&stats[64 + t], q0);
    }
}

// build A-frag: f0 = relu(a0*(v1+v2)+d0) for 8 channels starting at j0, packed bf16
__device__ inline bf16x8 build_af(const u16* __restrict__ V, int row1, int row2,
                                  const float* adt0, const float* adt1,
                                  const float* ngs, int j0) {
    float v1f[8], v2f[8];
    uint4 q1 = *(const uint4*)(V + (size_t)row1 * 128 + j0);
    unp8(q1, v1f);
    if (row2 >= 0) {
        uint4 q2 = *(const uint4*)(V + (size_t)row2 * 128 + 64 + j0);
        unp8(q2, v2f);
    } else {
        #pragma unroll
        for (int i = 0; i < 8; ++i) v2f[i] = ngs[j0 + i];
    }
    bf16x8 r;
    #pragma unroll
    for (int i = 0; i < 8; ++i) {
        float f0 = fmaxf((v1f[i] + v2f[i]) * adt0[j0 + i] + adt1[j0 + i], 0.f);
        r[i] = (short)f2b(f0);
    }
    return r;
}

// ---------------- P2: f0 -> z1 = f0 @ W1^T (MFMA), stats1 only ----------------
__global__ __launch_bounds__(256) void p2_kernel(const u16* __restrict__ V,
                                                 const int* __restrict__ nidx,
                                                 const float* __restrict__ neg2,
                                                 const u16* __restrict__ pack,
                                                 const float* __restrict__ g0,
                                                 const float* __restrict__ beta0,
                                                 float* __restrict__ stats) {
    __shared__ float adt0[64], adt1[64], ngs[64];
    __shared__ float red[2][4][64];
    const int t = threadIdx.x, lane = t & 63, w = t >> 6;
    const int cb = lane & 15, kq = lane >> 4;
    if (t < 64) {
        float mu = stats[t] * INV_S, vr = stats[64 + t] * INV_S - mu * mu;
        float a = rsqrtf(vr + EPS_) * g0[t];
        adt0[t] = a; adt1[t] = beta0[t] - mu * a; ngs[t] = neg2[t];
    }
    __syncthreads();
    const int b = blockIdx.y;
    const int slb = blockIdx.x * 192 + w * 48;
    const uint4* w1p = (const uint4*)(pack + W1P_OFF);

    bf16x8 bf[4][2];
    #pragma unroll
    for (int ct = 0; ct < 4; ++ct)
        #pragma unroll
        for (int kk = 0; kk < 2; ++kk)
            bf[ct][kk] = __builtin_bit_cast(bf16x8, w1p[(ct * 2 + kk) * 64 + lane]);

    f32x4 acc[3][4] = {};
    #pragma unroll
    for (int mt = 0; mt < 3; ++mt) {
        int sl = slb + mt * 16 + cb;
        int n = sl / 6;
        int m = nidx[sl];
        int row1 = b * N_ + n;
        int row2 = (m < N_) ? (b * N_ + m) : -1;
        bf16x8 af[2];
        #pragma unroll
        for (int kk = 0; kk < 2; ++kk)
            af[kk] = build_af(V, row1, row2, adt0, adt1, ngs, kk * 32 + kq * 8);
        #pragma unroll
        for (int ct = 0; ct < 4; ++ct) {
            acc[mt][ct] = __builtin_amdgcn_mfma_f32_16x16x32_bf16(af[0], bf[ct][0], acc[mt][ct], 0, 0, 0);
            acc[mt][ct] = __builtin_amdgcn_mfma_f32_16x16x32_bf16(af[1], bf[ct][1], acc[mt][ct], 0, 0, 0);
        }
    }
    float ssum[4] = {0,0,0,0}, ssq[4] = {0,0,0,0};
    #pragma unroll
    for (int mt = 0; mt < 3; ++mt)
        #pragma unroll
        for (int ct = 0; ct < 4; ++ct)
            #pragma unroll
            for (int r = 0; r < 4; ++r) {
                float z = acc[mt][ct][r];
                ssum[ct] += z; ssq[ct] += z * z;
            }
    #pragma unroll
    for (int ct = 0; ct < 4; ++ct) {
        ssum[ct] += __shfl_xor(ssum[ct], 16); ssum[ct] += __shfl_xor(ssum[ct], 32);
        ssq[ct]  += __shfl_xor(ssq[ct], 16);  ssq[ct]  += __shfl_xor(ssq[ct], 32);
    }
    if (lane < 16) {
        #pragma unroll
        for (int ct = 0; ct < 4; ++ct) {
            red[0][w][ct * 16 + lane] = ssum[ct];
            red[1][w][ct * 16 + lane] = ssq[ct];
        }
    }
    __syncthreads();
    if (t < 64) {
        float s = (red[0][0][t] + red[0][1][t]) + (red[0][2][t] + red[0][3][t]);
        float q = (red[1][0][t] + red[1][1][t]) + (red[1][2][t] + red[1][3][t]);
        atomicAdd(&stats[128 + t], s);
        atomicAdd(&stats[192 + t], q);
    }
}

// ---------------- P3: f0 -> z1 -> f1 -> z2 (MFMA x2), stats2, sign-max over k ----------------
__global__ __launch_bounds__(256) void p3_kernel(const u16* __restrict__ V,
                                                 const int* __restrict__ nidx,
                                                 const float* __restrict__ neg2,
                                                 const u16* __restrict__ pack,
                                                 const float* __restrict__ g0, const float* __restrict__ beta0,
                                                 const float* __restrict__ g1, const float* __restrict__ beta1,
                                                 const float* __restrict__ g2,
                                                 float* __restrict__ stats,
                                                 float* __restrict__ out) {
    __shared__ u16  f1s[4][3072];            // per-wave 48x64 bf16, XOR-swizzled
    __shared__ uint bmax[32][128];           // per-block sign-adjusted max (fmap'd)
    __shared__ float adt0[64], adt1[64], adt2[64], adt3[64], ngs[64];
    __shared__ float psign[128];
    __shared__ float red[2][4][128];
    const int t = threadIdx.x, lane = t & 63, w = t >> 6;
    const int cb = lane & 15, kq = lane >> 4;
    if (t < 64) {
        float mu0 = stats[t] * INV_S, vr0 = stats[64 + t] * INV_S - mu0 * mu0;
        float a0 = rsqrtf(vr0 + EPS_) * g0[t];
        adt0[t] = a0; adt1[t] = beta0[t] - mu0 * a0;
        float mu1 = stats[128 + t] * INV_S, vr1 = stats[192 + t] * INV_S - mu1 * mu1;
        float a1 = rsqrtf(vr1 + EPS_) * g1[t];
        adt2[t] = a1; adt3[t] = beta1[t] - mu1 * a1;
        ngs[t] = neg2[t];
    }
    if (t < 128) psign[t] = (g2[t] >= 0.f) ? 1.f : -1.f;
    #pragma unroll
    for (int i = 0; i < 16; ++i) ((uint*)bmax)[t + 256 * i] = 0u;
    __syncthreads();

    const int b = blockIdx.y;
    const int slb = blockIdx.x * 192 + w * 48;
    const uint4* w1p = (const uint4*)(pack + W1P_OFF);
    const uint4* w2p = (const uint4*)(pack + W2P_OFF);

    // ---- front: z1 = f0 @ W1^T ----
    bf16x8 bf1[4][2];
    #pragma unroll
    for (int ct = 0; ct < 4; ++ct)
        #pragma unroll
        for (int kk = 0; kk < 2; ++kk)
            bf1[ct][kk] = __builtin_bit_cast(bf16x8, w1p[(ct * 2 + kk) * 64 + lane]);
    f32x4 acc1[3][4] = {};
    #pragma unroll
    for (int mt = 0; mt < 3; ++mt) {
        int sl = slb + mt * 16 + cb;
        int n = sl / 6;
        int m = nidx[sl];
        int row1 = b * N_ + n;
        int row2 = (m < N_) ? (b * N_ + m) : -1;
        bf16x8 af[2];
        #pragma unroll
        for (int kk = 0; kk < 2; ++kk)
            af[kk] = build_af(V, row1, row2, adt0, adt1, ngs, kk * 32 + kq * 8);
        #pragma unroll
        for (int ct = 0; ct < 4; ++ct) {
            acc1[mt][ct] = __builtin_amdgcn_mfma_f32_16x16x32_bf16(af[0], bf1[ct][0], acc1[mt][ct], 0, 0, 0);
            acc1[mt][ct] = __builtin_amdgcn_mfma_f32_16x16x32_bf16(af[1], bf1[ct][1], acc1[mt][ct], 0, 0, 0);
        }
    }
    // ---- BN1 + ReLU -> f1 into wave-local LDS (XOR swizzle on 8-row stripes) ----
    u16* fb = f1s[w];
    #pragma unroll
    for (int mt = 0; mt < 3; ++mt)
        #pragma unroll
        for (int ct = 0; ct < 4; ++ct) {
            float a1c = adt2[ct * 16 + cb], d1c = adt3[ct * 16 + cb];
            #pragma unroll
            for (int r = 0; r < 4; ++r) {
                float f1 = fmaxf(acc1[mt][ct][r] * a1c + d1c, 0.f);
                int rl = mt * 16 + kq * 4 + r;
                fb[rl * 64 + ((ct * 16 + cb) ^ ((rl & 7) << 3))] = f2b(f1);
            }
        }
    // ---- back: z2 = f1 @ W2^T, two 64-col halves ----
    float ssum[8] = {0,0,0,0,0,0,0,0}, ssq[8] = {0,0,0,0,0,0,0,0};
    #pragma unroll
    for (int half = 0; half < 2; ++half) {
        bf16x8 bf2[4][2];
        #pragma unroll
        for (int ct = 0; ct < 4; ++ct)
            #pragma unroll
            for (int kk = 0; kk < 2; ++kk)
                bf2[ct][kk] = __builtin_bit_cast(bf16x8, w2p[((half * 4 + ct) * 2 + kk) * 64 + lane]);
        f32x4 acc2[3][4] = {};
        #pragma unroll
        for (int mt = 0; mt < 3; ++mt) {
            int rl = mt * 16 + cb;
            bf16x8 af2[2];
            #pragma unroll
            for (int kk = 0; kk < 2; ++kk) {
                int j0 = kk * 32 + kq * 8;
                uint4 q = *(const uint4*)(fb + rl * 64 + (j0 ^ ((rl & 7) << 3)));
                af2[kk] = __builtin_bit_cast(bf16x8, q);
            }
            #pragma unroll
            for (int ct = 0; ct < 4; ++ct) {
                acc2[mt][ct] = __builtin_amdgcn_mfma_f32_16x16x32_bf16(af2[0], bf2[ct][0], acc2[mt][ct], 0, 0, 0);
                acc2[mt][ct] = __builtin_amdgcn_mfma_f32_16x16x32_bf16(af2[1], bf2[ct][1], acc2[mt][ct], 0, 0, 0);
            }
        }
        #pragma unroll
        for (int ct = 0; ct < 4; ++ct) {
            int c2 = half * 64 + ct * 16 + cb;
            float ps = psign[c2];
            #pragma unroll
            for (int mt = 0; mt < 3; ++mt) {
                int base = mt * 16 + kq * 4;              // row base within wave tile
                int nb = 6 - (base % 6); nb = (nb > 4) ? 4 : nb;   // rows of first point
                int nl = w * 8 + base / 6;                // point slot in bmax
                float m1 = -3.402823466e+38f, m2 = -3.402823466e+38f;
                #pragma unroll
                for (int r = 0; r < 4; ++r) {
                    float z = acc2[mt][ct][r];
                    ssum[half * 4 + ct] += z;
                    ssq[half * 4 + ct] += z * z;
                    float zz = z * ps;
                    m1 = (r < nb) ? fmaxf(m1, zz) : m1;
                    m2 = (r < nb) ? m2 : fmaxf(m2, zz);
                }
                atomicMax(&bmax[nl][c2], fmap(m1));
                if (nb < 4) atomicMax(&bmax[nl + 1][c2], fmap(m2));
            }
        }
    }
    // ---- stats2 reduce ----
    #pragma unroll
    for (int j = 0; j < 8; ++j) {
        ssum[j] += __shfl_xor(ssum[j], 16); ssum[j] += __shfl_xor(ssum[j], 32);
        ssq[j]  += __shfl_xor(ssq[j], 16);  ssq[j]  += __shfl_xor(ssq[j], 32);
    }
    if (lane < 16) {
        #pragma unroll
        for (int j = 0; j < 8; ++j) {
            int c = (j >> 2) * 64 + (j & 3) * 16 + lane;
            red[0][w][c] = ssum[j];
            red[1][w][c] = ssq[j];
        }
    }
    __syncthreads();
    if (t < 128) {
        float s = (red[0][0][t] + red[0][1][t]) + (red[0][2][t] + red[0][3][t]);
        float q = (red[1][0][t] + red[1][1][t]) + (red[1][2][t] + red[1][3][t]);
        atomicAdd(&stats[256 + t], s);
        atomicAdd(&stats[384 + t], q);
    }
    // ---- write raw sign-max: out[b][c2][n0..n0+31] ----
    {
        int c2 = t >> 1, nh = t & 1;
        float ps = psign[c2];
        float* op = out + OF_ + ((size_t)b * 128 + c2) * N_ + blockIdx.x * 32 + nh * 16;
        #pragma unroll
        for (int i4 = 0; i4 < 4; ++i4) {
            float4 v;
            v.x = funmap(bmax[nh * 16 + i4 * 4 + 0][c2]) * ps;
            v.y = funmap(bmax[nh * 16 + i4 * 4 + 1][c2]) * ps;
            v.z = funmap(bmax[nh * 16 + i4 * 4 + 2][c2]) * ps;
            v.w = funmap(bmax[nh * 16 + i4 * 4 + 3][c2]) * ps;
            *(float4*)(op + i4 * 4) = v;
        }
    }
}

// ---------------- P4: normalize new_feature in place + channel max ----------------
__global__ __launch_bounds__(256) void p4_kernel(const float* __restrict__ g2,
                                                 const float* __restrict__ beta2,
                                                 const float* __restrict__ stats,
                                                 float* __restrict__ outbuf) {
    __shared__ float a2s[128], d2s[128];
    const int t = threadIdx.x;
    if (t < 128) {
        float mu = stats[256 + t] * INV_S;
        float vr = stats[384 + t] * INV_S - mu * mu;
        float a = rsqrtf(vr + EPS_) * g2[t];
        a2s[t] = a;
        d2s[t] = beta2[t] - mu * a;
    }
    __syncthreads();
    const int b = blockIdx.y;
    const int n = blockIdx.x * 256 + t;
    if (n >= N_) return;
    float vmax = -3.402823466e+38f;
    #pragma unroll 8
    for (int c2 = 0; c2 < 128; ++c2) {
        size_t idx = OF_ + ((size_t)b * 128 + c2) * N_ + n;
        float v = fmaxf(outbuf[idx] * a2s[c2] + d2s[c2], 0.f);
        outbuf[idx] = v;
        vmax = fmaxf(vmax, v);
    }
    outbuf[b * N_ + n] = vmax;
}

extern "C" void kernel_launch(void* const* d_in, const int* in_sizes, int n_in,
                              void* d_out, int out_size, void* d_ws, size_t ws_size,
                              hipStream_t stream) {
    (void)in_sizes; (void)n_in; (void)out_size; (void)ws_size;
    const float* pts   = (const float*)d_in[0];
    const int*   nidx  = (const int*)d_in[1];
    const float* W0    = (const float*)d_in[2];
    const float* g0    = (const float*)d_in[4];
    const float* beta0 = (const float*)d_in[5];
    const float* W1    = (const float*)d_in[6];
    const float* g1    = (const float*)d_in[8];
    const float* beta1 = (const float*)d_in[9];
    const float* W2    = (const float*)d_in[10];
    const float* g2    = (const float*)d_in[12];
    const float* beta2 = (const float*)d_in[13];
    u16*   V     = (u16*)d_ws;
    float* stats = (float*)d_ws + WS_STATS_F;
    float* neg2  = (float*)d_ws + WS_NEG2_F;
    u16*   pack  = (u16*)d_ws + WS_PACK_U16;
    float* out   = (float*)d_out;

    hipLaunchKernelGGL(wprep_kernel, dim3(1), dim3(256), 0, stream, W0, W1, W2, stats, neg2, pack);
    hipLaunchKernelGGL(p0_kernel, dim3((N_ + 191) / 192, B_), dim3(256), 0, stream, pts, pack, V);
    hipLaunchKernelGGL(p1_kernel, dim3(N_ / 32, B_), dim3(256), 0, stream, V, nidx, neg2, stats);
    hipLaunchKernelGGL(p2_kernel, dim3(SPB / 192, B_), dim3(256), 0, stream, V, nidx, neg2, pack, g0, beta0, stats);
    hipLaunchKernelGGL(p3_kernel, dim3(SPB / 192, B_), dim3(256), 0, stream, V, nidx, neg2, pack,
                       g0, beta0, g1, beta1, g2, stats, out);
    hipLaunchKernelGGL(p4_kernel, dim3((N_ + 255) / 256, B_), dim3(256), 0, stream, g2, beta2, stats, out);
}

// Round 5
// 313.190 us; speedup vs baseline: 2.9624x; 1.1745x over previous
//
#include <hip/hip_runtime.h>

typedef unsigned short u16;
typedef unsigned int uint;
typedef short bf16x8 __attribute__((ext_vector_type(8)));
typedef float f32x4 __attribute__((ext_vector_type(4)));

constexpr int B_ = 2;
constexpr int N_ = 40000;
constexpr int SPB = 240000;            // samples per batch = N*6
constexpr int S_ = B_ * SPB;           // 480000 BN samples
constexpr float EPS_ = 1e-5f;
constexpr float INV_S = 1.0f / (float)S_;
constexpr int OF_ = B_ * N_;           // out_feature elems before new_feature
constexpr int TILES_PB = SPB / 48;     // 5000 wave-tiles per batch

// ws layouts (u16 units unless noted):
//   V bf16 [B*N][128]: [0, 10,240,000)
//   big path: f0 frags [10,240,000, 40,960,000); stats f32@20,480,000; neg2 f32@+512; pack@40,961,152
//   small path: stats f32@5,120,000; neg2 f32@+512; pack@10,241,152
constexpr int      WS_V_U16   = B_ * N_ * 128;
constexpr size_t   NEED_BIG_B = 81955072ull;

// ---------- helpers ----------
__device__ inline float b2f_lo(uint u) { return __builtin_bit_cast(float, u << 16); }
__device__ inline float b2f_hi(uint u) { return __builtin_bit_cast(float, u & 0xffff0000u); }
__device__ inline u16 f2b(float f) {   // RNE float->bf16
    uint b = __builtin_bit_cast(uint, f);
    return (u16)((b + 0x7fffu + ((b >> 16) & 1u)) >> 16);
}
__device__ inline void unp8(uint4 q, float* f) {
    f[0] = b2f_lo(q.x); f[1] = b2f_hi(q.x); f[2] = b2f_lo(q.y); f[3] = b2f_hi(q.y);
    f[4] = b2f_lo(q.z); f[5] = b2f_hi(q.z); f[6] = b2f_lo(q.w); f[7] = b2f_hi(q.w);
}
// monotone float<->uint map for atomicMax-based float max
__device__ inline uint fmap(float f) {
    int i = __float_as_int(f);
    return (i >= 0) ? ((uint)i | 0x80000000u) : ~(uint)i;
}
__device__ inline float funmap(uint u) {
    int i = (u & 0x80000000u) ? (int)(u & 0x7fffffffu) : (int)~u;
    return __int_as_float(i);
}

// ---------------- WPREP: zero stats, neg2, pack M/W1/W2 into fragment-ordered bf16 ----------------
__global__ __launch_bounds__(256) void wprep_kernel(const float* __restrict__ W0,
                                                    const float* __restrict__ W1,
                                                    const float* __restrict__ W2,
                                                    float* __restrict__ stats,
                                                    float* __restrict__ neg2,
                                                    u16* __restrict__ pack) {
    const int t = threadIdx.x;
    stats[t] = 0.f; stats[t + 256] = 0.f;
    if (t < 64) {
        float s = 0.f;
        for (int j = 0; j < 64; ++j) s += W0[t * 128 + 64 + j];
        neg2[t] = -s;
    }
    for (int g = t; g < 40 * 64; g += 256) {
        int lane = g & 63, grp = g >> 6;
        int cb = lane & 15, kq = lane >> 4;
        ushort4 lo, hi;
        u16* dst;
        if (grp < 16) {
            int ct = grp >> 1, kk = grp & 1;
            int c = ct * 16 + cb, jb = kk * 32 + kq * 8;
            dst = pack + g * 8;
            float v[8];
            #pragma unroll
            for (int i = 0; i < 8; ++i)
                v[i] = (c < 64) ? W0[c * 128 + jb + i] : W0[(c - 64) * 128 + 64 + jb + i];
            lo = {f2b(v[0]), f2b(v[1]), f2b(v[2]), f2b(v[3])};
            hi = {f2b(v[4]), f2b(v[5]), f2b(v[6]), f2b(v[7])};
        } else if (grp < 24) {
            int g2 = grp - 16;
            int ct = g2 >> 1, kk = g2 & 1;
            const float* wp = W1 + (ct * 16 + cb) * 64 + kk * 32 + kq * 8;
            dst = pack + 8192 + (g2 * 64 + lane) * 8;
            lo = {f2b(wp[0]), f2b(wp[1]), f2b(wp[2]), f2b(wp[3])};
            hi = {f2b(wp[4]), f2b(wp[5]), f2b(wp[6]), f2b(wp[7])};
        } else {
            int g3 = grp - 24;
            int ct = g3 >> 1, kk = g3 & 1;
            const float* wp = W2 + (ct * 16 + cb) * 64 + kk * 32 + kq * 8;
            dst = pack + 12288 + (g3 * 64 + lane) * 8;
            lo = {f2b(wp[0]), f2b(wp[1]), f2b(wp[2]), f2b(wp[3])};
            hi = {f2b(wp[4]), f2b(wp[5]), f2b(wp[6]), f2b(wp[7])};
        }
        *(ushort4*)dst = lo;
        *(ushort4*)(dst + 4) = hi;
    }
}

// ---------------- P0 (MFMA): V[point][c] = M @ x ----------------
__global__ __launch_bounds__(256) void p0_kernel(const float* __restrict__ pts,
                                                 const u16* __restrict__ pack,
                                                 u16* __restrict__ V) {
    const int t = threadIdx.x, lane = t & 63, w = t >> 6;
    const int cb = lane & 15, kq = lane >> 4;
    const int b = blockIdx.y;
    const int n0 = blockIdx.x * 192 + w * 48;
    const uint4* mp = (const uint4*)pack;

    bf16x8 af[3][2];
    #pragma unroll
    for (int mt = 0; mt < 3; ++mt) {
        int n = n0 + mt * 16 + cb;
        int nc = (n < N_) ? n : (N_ - 1);
        const float* xp = pts + b * 64 * N_ + nc;
        #pragma unroll
        for (int kk = 0; kk < 2; ++kk) {
            int jb = kk * 32 + kq * 8;
            #pragma unroll
            for (int i = 0; i < 8; ++i)
                af[mt][kk][i] = (short)f2b(xp[(size_t)(jb + i) * N_]);
        }
    }
    #pragma unroll
    for (int ct = 0; ct < 8; ++ct) {
        bf16x8 b0 = __builtin_bit_cast(bf16x8, mp[(ct * 2 + 0) * 64 + lane]);
        bf16x8 b1 = __builtin_bit_cast(bf16x8, mp[(ct * 2 + 1) * 64 + lane]);
        #pragma unroll
        for (int mt = 0; mt < 3; ++mt) {
            f32x4 acc = {};
            acc = __builtin_amdgcn_mfma_f32_16x16x32_bf16(af[mt][0], b0, acc, 0, 0, 0);
            acc = __builtin_amdgcn_mfma_f32_16x16x32_bf16(af[mt][1], b1, acc, 0, 0, 0);
            int rbase = n0 + mt * 16 + kq * 4;
            #pragma unroll
            for (int r = 0; r < 4; ++r) {
                int n = rbase + r;
                if (n < N_) V[(size_t)(b * N_ + n) * 128 + ct * 16 + cb] = f2b(acc[r]);
            }
        }
    }
}

// ---------------- P1: stats of z0, slot-based uint4 gather ----------------
// 64 lanes = 8 slots (samples) x 8 channel-groups; per block: 4 waves x 12 iters x 8 = 384 samples
__global__ __launch_bounds__(256) void p1_kernel(const u16* __restrict__ V,
                                                 const int* __restrict__ nidx,
                                                 const float* __restrict__ neg2,
                                                 float* __restrict__ stats) {
    const int t = threadIdx.x, lane = t & 63, w = t >> 6;
    const int slot = lane >> 3, cg = lane & 7;
    const int b = blockIdx.y;
    const int s0 = blockIdx.x * 384 + w * 96;
    float ngs8[8];
    #pragma unroll
    for (int i = 0; i < 8; ++i) ngs8[i] = neg2[cg * 8 + i];
    float sum[8] = {0,0,0,0,0,0,0,0}, sq[8] = {0,0,0,0,0,0,0,0};
    #pragma unroll 4
    for (int it = 0; it < 12; ++it) {
        int s = s0 + it * 8 + slot;
        int n = s / 6;
        int m = nidx[s];
        bool valid = (m < N_);
        int row2 = valid ? (b * N_ + m) : 0;
        uint4 q1 = *(const uint4*)(V + (size_t)(b * N_ + n) * 128 + cg * 8);
        uint4 q2 = *(const uint4*)(V + (size_t)row2 * 128 + 64 + cg * 8);
        float v1[8], v2[8];
        unp8(q1, v1); unp8(q2, v2);
        #pragma unroll
        for (int i = 0; i < 8; ++i) {
            float z = v1[i] + (valid ? v2[i] : ngs8[i]);
            sum[i] += z; sq[i] = fmaf(z, z, sq[i]);
        }
    }
    #pragma unroll
    for (int i = 0; i < 8; ++i) {
        sum[i] += __shfl_xor(sum[i], 8); sum[i] += __shfl_xor(sum[i], 16); sum[i] += __shfl_xor(sum[i], 32);
        sq[i]  += __shfl_xor(sq[i], 8);  sq[i]  += __shfl_xor(sq[i], 16);  sq[i]  += __shfl_xor(sq[i], 32);
    }
    __shared__ float red[2][4][64];
    if (slot == 0) {
        #pragma unroll
        for (int i = 0; i < 8; ++i) { red[0][w][cg * 8 + i] = sum[i]; red[1][w][cg * 8 + i] = sq[i]; }
    }
    __syncthreads();
    if (t < 64) {
        float s_ = (red[0][0][t] + red[0][1][t]) + (red[0][2][t] + red[0][3][t]);
        float q_ = (red[1][0][t] + red[1][1][t]) + (red[1][2][t] + red[1][3][t]);
        atomicAdd(&stats[t], s_);
        atomicAdd(&stats[64 + t], q_);
    }
}

// build A-frag: f0 = relu(a0*(v1+v2)+d0) for 8 channels starting at j0, packed bf16
__device__ inline bf16x8 build_af(const u16* __restrict__ V, int row1, int row2,
                                  const float* adt0, const float* adt1,
                                  const float* ngs, int j0) {
    float v1f[8], v2f[8];
    uint4 q1 = *(const uint4*)(V + (size_t)row1 * 128 + j0);
    unp8(q1, v1f);
    if (row2 >= 0) {
        uint4 q2 = *(const uint4*)(V + (size_t)row2 * 128 + 64 + j0);
        unp8(q2, v2f);
    } else {
        #pragma unroll
        for (int i = 0; i < 8; ++i) v2f[i] = ngs[j0 + i];
    }
    bf16x8 r;
    #pragma unroll
    for (int i = 0; i < 8; ++i) {
        float f0 = fmaxf((v1f[i] + v2f[i]) * adt0[j0 + i] + adt1[j0 + i], 0.f);
        r[i] = (short)f2b(f0);
    }
    return r;
}

// ---------------- P2: f0 -> z1 (MFMA), stats1; optionally store f0 frags ----------------
template<int STOREF0>
__global__ __launch_bounds__(256) void p2_kernel(const u16* __restrict__ V,
                                                 const int* __restrict__ nidx,
                                                 const float* __restrict__ neg2,
                                                 const u16* __restrict__ pack,
                                                 const float* __restrict__ g0,
                                                 const float* __restrict__ beta0,
                                                 float* __restrict__ stats,
                                                 u16* __restrict__ f0buf) {
    __shared__ float adt0[64], adt1[64], ngs[64];
    __shared__ float red[2][4][64];
    const int t = threadIdx.x, lane = t & 63, w = t >> 6;
    const int cb = lane & 15, kq = lane >> 4;
    if (t < 64) {
        float mu = stats[t] * INV_S, vr = stats[64 + t] * INV_S - mu * mu;
        float a = rsqrtf(vr + EPS_) * g0[t];
        adt0[t] = a; adt1[t] = beta0[t] - mu * a; ngs[t] = neg2[t];
    }
    __syncthreads();
    const int b = blockIdx.y;
    const int slb = blockIdx.x * 192 + w * 48;
    const uint4* w1p = (const uint4*)(pack + 8192);
    uint4* ftile = STOREF0 ? ((uint4*)f0buf + ((size_t)b * TILES_PB + blockIdx.x * 4 + w) * (6 * 64)) : nullptr;

    bf16x8 bf[4][2];
    #pragma unroll
    for (int ct = 0; ct < 4; ++ct)
        #pragma unroll
        for (int kk = 0; kk < 2; ++kk)
            bf[ct][kk] = __builtin_bit_cast(bf16x8, w1p[(ct * 2 + kk) * 64 + lane]);

    f32x4 acc[3][4] = {};
    #pragma unroll
    for (int mt = 0; mt < 3; ++mt) {
        int sl = slb + mt * 16 + cb;
        int n = sl / 6;
        int m = nidx[sl];
        int row1 = b * N_ + n;
        int row2 = (m < N_) ? (b * N_ + m) : -1;
        bf16x8 af[2];
        #pragma unroll
        for (int kk = 0; kk < 2; ++kk) {
            af[kk] = build_af(V, row1, row2, adt0, adt1, ngs, kk * 32 + kq * 8);
            if constexpr (STOREF0)
                ftile[(mt * 2 + kk) * 64 + lane] = __builtin_bit_cast(uint4, af[kk]);
        }
        #pragma unroll
        for (int ct = 0; ct < 4; ++ct) {
            acc[mt][ct] = __builtin_amdgcn_mfma_f32_16x16x32_bf16(af[0], bf[ct][0], acc[mt][ct], 0, 0, 0);
            acc[mt][ct] = __builtin_amdgcn_mfma_f32_16x16x32_bf16(af[1], bf[ct][1], acc[mt][ct], 0, 0, 0);
        }
    }
    float ssum[4] = {0,0,0,0}, ssq[4] = {0,0,0,0};
    #pragma unroll
    for (int mt = 0; mt < 3; ++mt)
        #pragma unroll
        for (int ct = 0; ct < 4; ++ct)
            #pragma unroll
            for (int r = 0; r < 4; ++r) {
                float z = acc[mt][ct][r];
                ssum[ct] += z; ssq[ct] += z * z;
            }
    #pragma unroll
    for (int ct = 0; ct < 4; ++ct) {
        ssum[ct] += __shfl_xor(ssum[ct], 16); ssum[ct] += __shfl_xor(ssum[ct], 32);
        ssq[ct]  += __shfl_xor(ssq[ct], 16);  ssq[ct]  += __shfl_xor(ssq[ct], 32);
    }
    if (lane < 16) {
        #pragma unroll
        for (int ct = 0; ct < 4; ++ct) {
            red[0][w][ct * 16 + lane] = ssum[ct];
            red[1][w][ct * 16 + lane] = ssq[ct];
        }
    }
    __syncthreads();
    if (t < 64) {
        float s = (red[0][0][t] + red[0][1][t]) + (red[0][2][t] + red[0][3][t]);
        float q = (red[1][0][t] + red[1][1][t]) + (red[1][2][t] + red[1][3][t]);
        atomicAdd(&stats[128 + t], s);
        atomicAdd(&stats[192 + t], q);
    }
}

// ---------------- P3: f0 -> z1 -> f1 -> z2 (MFMA x2), stats2, sign-max over k ----------------
template<int LOADF0>
__global__ __launch_bounds__(256) void p3_kernel(const u16* __restrict__ V,
                                                 const int* __restrict__ nidx,
                                                 const float* __restrict__ neg2,
                                                 const u16* __restrict__ pack,
                                                 const float* __restrict__ g0, const float* __restrict__ beta0,
                                                 const float* __restrict__ g1, const float* __restrict__ beta1,
                                                 const float* __restrict__ g2,
                                                 float* __restrict__ stats,
                                                 const u16* __restrict__ f0buf,
                                                 float* __restrict__ out) {
    __shared__ u16  f1s[4][3072];            // per-wave 48x64 bf16, XOR-swizzled
    __shared__ uint bmax[32][128];           // per-block sign-adjusted max (fmap'd)
    __shared__ float adt0[64], adt1[64], adt2[64], adt3[64], ngs[64];
    __shared__ float psign[128];
    __shared__ float red[2][4][128];
    const int t = threadIdx.x, lane = t & 63, w = t >> 6;
    const int cb = lane & 15, kq = lane >> 4;
    if (t < 64) {
        if constexpr (!LOADF0) {
            float mu0 = stats[t] * INV_S, vr0 = stats[64 + t] * INV_S - mu0 * mu0;
            float a0 = rsqrtf(vr0 + EPS_) * g0[t];
            adt0[t] = a0; adt1[t] = beta0[t] - mu0 * a0;
            ngs[t] = neg2[t];
        }
        float mu1 = stats[128 + t] * INV_S, vr1 = stats[192 + t] * INV_S - mu1 * mu1;
        float a1 = rsqrtf(vr1 + EPS_) * g1[t];
        adt2[t] = a1; adt3[t] = beta1[t] - mu1 * a1;
    }
    if (t < 128) psign[t] = (g2[t] >= 0.f) ? 1.f : -1.f;
    #pragma unroll
    for (int i = 0; i < 16; ++i) ((uint*)bmax)[t + 256 * i] = 0u;
    __syncthreads();

    const int b = blockIdx.y;
    const int slb = blockIdx.x * 192 + w * 48;
    const uint4* w1p = (const uint4*)(pack + 8192);
    const uint4* w2p = (const uint4*)(pack + 12288);
    const uint4* ftile = LOADF0 ? ((const uint4*)f0buf + ((size_t)b * TILES_PB + blockIdx.x * 4 + w) * (6 * 64)) : nullptr;

    // ---- front: z1 = f0 @ W1^T ----
    bf16x8 bf1[4][2];
    #pragma unroll
    for (int ct = 0; ct < 4; ++ct)
        #pragma unroll
        for (int kk = 0; kk < 2; ++kk)
            bf1[ct][kk] = __builtin_bit_cast(bf16x8, w1p[(ct * 2 + kk) * 64 + lane]);
    f32x4 acc1[3][4] = {};
    #pragma unroll
    for (int mt = 0; mt < 3; ++mt) {
        bf16x8 af[2];
        if constexpr (LOADF0) {
            af[0] = __builtin_bit_cast(bf16x8, ftile[(mt * 2 + 0) * 64 + lane]);
            af[1] = __builtin_bit_cast(bf16x8, ftile[(mt * 2 + 1) * 64 + lane]);
        } else {
            int sl = slb + mt * 16 + cb;
            int n = sl / 6;
            int m = nidx[sl];
            int row1 = b * N_ + n;
            int row2 = (m < N_) ? (b * N_ + m) : -1;
            #pragma unroll
            for (int kk = 0; kk < 2; ++kk)
                af[kk] = build_af(V, row1, row2, adt0, adt1, ngs, kk * 32 + kq * 8);
        }
        #pragma unroll
        for (int ct = 0; ct < 4; ++ct) {
            acc1[mt][ct] = __builtin_amdgcn_mfma_f32_16x16x32_bf16(af[0], bf1[ct][0], acc1[mt][ct], 0, 0, 0);
            acc1[mt][ct] = __builtin_amdgcn_mfma_f32_16x16x32_bf16(af[1], bf1[ct][1], acc1[mt][ct], 0, 0, 0);
        }
    }
    // ---- BN1 + ReLU -> f1 into wave-local LDS (XOR swizzle on 8-row stripes) ----
    u16* fb = f1s[w];
    #pragma unroll
    for (int mt = 0; mt < 3; ++mt)
        #pragma unroll
        for (int ct = 0; ct < 4; ++ct) {
            float a1c = adt2[ct * 16 + cb], d1c = adt3[ct * 16 + cb];
            #pragma unroll
            for (int r = 0; r < 4; ++r) {
                float f1 = fmaxf(acc1[mt][ct][r] * a1c + d1c, 0.f);
                int rl = mt * 16 + kq * 4 + r;
                fb[rl * 64 + ((ct * 16 + cb) ^ ((rl & 7) << 3))] = f2b(f1);
            }
        }
    // ---- back: z2 = f1 @ W2^T, two 64-col halves ----
    float ssum[8] = {0,0,0,0,0,0,0,0}, ssq[8] = {0,0,0,0,0,0,0,0};
    #pragma unroll
    for (int half = 0; half < 2; ++half) {
        bf16x8 bf2[4][2];
        #pragma unroll
        for (int ct = 0; ct < 4; ++ct)
            #pragma unroll
            for (int kk = 0; kk < 2; ++kk)
                bf2[ct][kk] = __builtin_bit_cast(bf16x8, w2p[((half * 4 + ct) * 2 + kk) * 64 + lane]);
        f32x4 acc2[3][4] = {};
        #pragma unroll
        for (int mt = 0; mt < 3; ++mt) {
            int rl = mt * 16 + cb;
            bf16x8 af2[2];
            #pragma unroll
            for (int kk = 0; kk < 2; ++kk) {
                int j0 = kk * 32 + kq * 8;
                uint4 q = *(const uint4*)(fb + rl * 64 + (j0 ^ ((rl & 7) << 3)));
                af2[kk] = __builtin_bit_cast(bf16x8, q);
            }
            #pragma unroll
            for (int ct = 0; ct < 4; ++ct) {
                acc2[mt][ct] = __builtin_amdgcn_mfma_f32_16x16x32_bf16(af2[0], bf2[ct][0], acc2[mt][ct], 0, 0, 0);
                acc2[mt][ct] = __builtin_amdgcn_mfma_f32_16x16x32_bf16(af2[1], bf2[ct][1], acc2[mt][ct], 0, 0, 0);
            }
        }
        #pragma unroll
        for (int ct = 0; ct < 4; ++ct) {
            int c2 = half * 64 + ct * 16 + cb;
            float ps = psign[c2];
            #pragma unroll
            for (int mt = 0; mt < 3; ++mt) {
                int base = mt * 16 + kq * 4;
                int nb = 6 - (base % 6); nb = (nb > 4) ? 4 : nb;
                int nl = w * 8 + base / 6;
                float m1 = -3.402823466e+38f, m2 = -3.402823466e+38f;
                #pragma unroll
                for (int r = 0; r < 4; ++r) {
                    float z = acc2[mt][ct][r];
                    ssum[half * 4 + ct] += z;
                    ssq[half * 4 + ct] += z * z;
                    float zz = z * ps;
                    m1 = (r < nb) ? fmaxf(m1, zz) : m1;
                    m2 = (r < nb) ? m2 : fmaxf(m2, zz);
                }
                atomicMax(&bmax[nl][c2], fmap(m1));
                if (nb < 4) atomicMax(&bmax[nl + 1][c2], fmap(m2));
            }
        }
    }
    // ---- stats2 reduce ----
    #pragma unroll
    for (int j = 0; j < 8; ++j) {
        ssum[j] += __shfl_xor(ssum[j], 16); ssum[j] += __shfl_xor(ssum[j], 32);
        ssq[j]  += __shfl_xor(ssq[j], 16);  ssq[j]  += __shfl_xor(ssq[j], 32);
    }
    if (lane < 16) {
        #pragma unroll
        for (int j = 0; j < 8; ++j) {
            int c = (j >> 2) * 64 + (j & 3) * 16 + lane;
            red[0][w][c] = ssum[j];
            red[1][w][c] = ssq[j];
        }
    }
    __syncthreads();
    if (t < 128) {
        float s = (red[0][0][t] + red[0][1][t]) + (red[0][2][t] + red[0][3][t]);
        float q = (red[1][0][t] + red[1][1][t]) + (red[1][2][t] + red[1][3][t]);
        atomicAdd(&stats[256 + t], s);
        atomicAdd(&stats[384 + t], q);
    }
    // ---- write raw sign-max: out[b][c2][n0..n0+31] ----
    {
        int c2 = t >> 1, nh = t & 1;
        float ps = psign[c2];
        float* op = out + OF_ + ((size_t)b * 128 + c2) * N_ + blockIdx.x * 32 + nh * 16;
        #pragma unroll
        for (int i4 = 0; i4 < 4; ++i4) {
            float4 v;
            v.x = funmap(bmax[nh * 16 + i4 * 4 + 0][c2]) * ps;
            v.y = funmap(bmax[nh * 16 + i4 * 4 + 1][c2]) * ps;
            v.z = funmap(bmax[nh * 16 + i4 * 4 + 2][c2]) * ps;
            v.w = funmap(bmax[nh * 16 + i4 * 4 + 3][c2]) * ps;
            *(float4*)(op + i4 * 4) = v;
        }
    }
}

// ---------------- P4: normalize new_feature in place + channel max ----------------
__global__ __launch_bounds__(256) void p4_kernel(const float* __restrict__ g2,
                                                 const float* __restrict__ beta2,
                                                 const float* __restrict__ stats,
                                                 float* __restrict__ outbuf) {
    __shared__ float a2s[128], d2s[128];
    const int t = threadIdx.x;
    if (t < 128) {
        float mu = stats[256 + t] * INV_S;
        float vr = stats[384 + t] * INV_S - mu * mu;
        float a = rsqrtf(vr + EPS_) * g2[t];
        a2s[t] = a;
        d2s[t] = beta2[t] - mu * a;
    }
    __syncthreads();
    const int b = blockIdx.y;
    const int n = blockIdx.x * 256 + t;
    if (n >= N_) return;
    float vmax = -3.402823466e+38f;
    #pragma unroll 8
    for (int c2 = 0; c2 < 128; ++c2) {
        size_t idx = OF_ + ((size_t)b * 128 + c2) * N_ + n;
        float v = fmaxf(outbuf[idx] * a2s[c2] + d2s[c2], 0.f);
        outbuf[idx] = v;
        vmax = fmaxf(vmax, v);
    }
    outbuf[b * N_ + n] = vmax;
}

extern "C" void kernel_launch(void* const* d_in, const int* in_sizes, int n_in,
                              void* d_out, int out_size, void* d_ws, size_t ws_size,
                              hipStream_t stream) {
    (void)in_sizes; (void)n_in; (void)out_size;
    const float* pts   = (const float*)d_in[0];
    const int*   nidx  = (const int*)d_in[1];
    const float* W0    = (const float*)d_in[2];
    const float* g0    = (const float*)d_in[4];
    const float* beta0 = (const float*)d_in[5];
    const float* W1    = (const float*)d_in[6];
    const float* g1    = (const float*)d_in[8];
    const float* beta1 = (const float*)d_in[9];
    const float* W2    = (const float*)d_in[10];
    const float* g2    = (const float*)d_in[12];
    const float* beta2 = (const float*)d_in[13];
    const bool big = ws_size >= NEED_BIG_B;   // deterministic per-session branch
    u16*   V     = (u16*)d_ws;
    u16*   f0b   = big ? ((u16*)d_ws + WS_V_U16) : nullptr;
    float* stats = (float*)d_ws + (big ? 20480000 : 5120000);
    float* neg2  = stats + 512;
    u16*   pack  = (u16*)d_ws + (big ? 40961152 : 10241152);
    float* out   = (float*)d_out;

    hipLaunchKernelGGL(wprep_kernel, dim3(1), dim3(256), 0, stream, W0, W1, W2, stats, neg2, pack);
    hipLaunchKernelGGL(p0_kernel, dim3((N_ + 191) / 192, B_), dim3(256), 0, stream, pts, pack, V);
    hipLaunchKernelGGL(p1_kernel, dim3(SPB / 384, B_), dim3(256), 0, stream, V, nidx, neg2, stats);
    if (big) {
        hipLaunchKernelGGL((p2_kernel<1>), dim3(SPB / 192, B_), dim3(256), 0, stream,
                           V, nidx, neg2, pack, g0, beta0, stats, f0b);
        hipLaunchKernelGGL((p3_kernel<1>), dim3(SPB / 192, B_), dim3(256), 0, stream,
                           V, nidx, neg2, pack, g0, beta0, g1, beta1, g2, stats, f0b, out);
    } else {
        hipLaunchKernelGGL((p2_kernel<0>), dim3(SPB / 192, B_), dim3(256), 0, stream,
                           V, nidx, neg2, pack, g0, beta0, stats, f0b);
        hipLaunchKernelGGL((p3_kernel<0>), dim3(SPB / 192, B_), dim3(256), 0, stream,
                           V, nidx, neg2, pack, g0, beta0, g1, beta1, g2, stats, f0b, out);
    }
    hipLaunchKernelGGL(p4_kernel, dim3((N_ + 255) / 256, B_), dim3(256), 0, stream, g2, beta2, stats, out);
}

// Round 6
// 309.060 us; speedup vs baseline: 3.0020x; 1.0134x over previous
//
#include <hip/hip_runtime.h>

typedef unsigned short u16;
typedef unsigned int uint;
typedef short bf16x8 __attribute__((ext_vector_type(8)));
typedef float f32x4 __attribute__((ext_vector_type(4)));

constexpr int B_ = 2;
constexpr int N_ = 40000;
constexpr int SPB = 240000;            // samples per batch = N*6
constexpr int S_ = B_ * SPB;           // 480000 BN samples
constexpr float EPS_ = 1e-5f;
constexpr float INV_S = 1.0f / (float)S_;
constexpr int OF_ = B_ * N_;           // out_feature elems before new_feature
constexpr int TILES_PB = SPB / 48;     // 5000 wave-tiles per batch

// ws layouts (u16 units):
//   V bf16 [B*N][128]: [0, 10,240,000)
//   big: z1 frags bf16 [10,240,000, 40,960,000); stats f32 @ f32-idx 20,480,000; pack u16 @ 40,961,152
//   small: stats f32 @ f32-idx 5,120,000; pack u16 @ 10,241,152
constexpr int      WS_V_U16   = B_ * N_ * 128;
constexpr size_t   NEED_BIG_B = 81955072ull;

// ---------- helpers ----------
__device__ inline float b2f_lo(uint u) { return __builtin_bit_cast(float, u << 16); }
__device__ inline float b2f_hi(uint u) { return __builtin_bit_cast(float, u & 0xffff0000u); }
__device__ inline u16 f2b(float f) {   // RNE float->bf16
    uint b = __builtin_bit_cast(uint, f);
    return (u16)((b + 0x7fffu + ((b >> 16) & 1u)) >> 16);
}
__device__ inline void unp8(uint4 q, float* f) {
    f[0] = b2f_lo(q.x); f[1] = b2f_hi(q.x); f[2] = b2f_lo(q.y); f[3] = b2f_hi(q.y);
    f[4] = b2f_lo(q.z); f[5] = b2f_hi(q.z); f[6] = b2f_lo(q.w); f[7] = b2f_hi(q.w);
}

// ---------------- WPREP ----------------
__global__ __launch_bounds__(256) void wprep_kernel(const float* __restrict__ W0,
                                                    const float* __restrict__ W1,
                                                    const float* __restrict__ W2,
                                                    float* __restrict__ stats,
                                                    float* __restrict__ neg2,
                                                    u16* __restrict__ pack) {
    const int t = threadIdx.x;
    stats[t] = 0.f; stats[t + 256] = 0.f;
    if (t < 64) {
        float s = 0.f;
        for (int j = 0; j < 64; ++j) s += W0[t * 128 + 64 + j];
        neg2[t] = -s;
    }
    for (int g = t; g < 40 * 64; g += 256) {
        int lane = g & 63, grp = g >> 6;
        int cb = lane & 15, kq = lane >> 4;
        ushort4 lo, hi;
        u16* dst;
        if (grp < 16) {
            int ct = grp >> 1, kk = grp & 1;
            int c = ct * 16 + cb, jb = kk * 32 + kq * 8;
            dst = pack + g * 8;
            float v[8];
            #pragma unroll
            for (int i = 0; i < 8; ++i)
                v[i] = (c < 64) ? W0[c * 128 + jb + i] : W0[(c - 64) * 128 + 64 + jb + i];
            lo = {f2b(v[0]), f2b(v[1]), f2b(v[2]), f2b(v[3])};
            hi = {f2b(v[4]), f2b(v[5]), f2b(v[6]), f2b(v[7])};
        } else if (grp < 24) {
            int g2 = grp - 16;
            int ct = g2 >> 1, kk = g2 & 1;
            const float* wp = W1 + (ct * 16 + cb) * 64 + kk * 32 + kq * 8;
            dst = pack + 8192 + (g2 * 64 + lane) * 8;
            lo = {f2b(wp[0]), f2b(wp[1]), f2b(wp[2]), f2b(wp[3])};
            hi = {f2b(wp[4]), f2b(wp[5]), f2b(wp[6]), f2b(wp[7])};
        } else {
            int g3 = grp - 24;
            int ct = g3 >> 1, kk = g3 & 1;
            const float* wp = W2 + (ct * 16 + cb) * 64 + kk * 32 + kq * 8;
            dst = pack + 12288 + (g3 * 64 + lane) * 8;
            lo = {f2b(wp[0]), f2b(wp[1]), f2b(wp[2]), f2b(wp[3])};
            hi = {f2b(wp[4]), f2b(wp[5]), f2b(wp[6]), f2b(wp[7])};
        }
        *(ushort4*)dst = lo;
        *(ushort4*)(dst + 4) = hi;
    }
}

// ---------------- P0 (MFMA): V = M @ x ----------------
__global__ __launch_bounds__(256) void p0_kernel(const float* __restrict__ pts,
                                                 const u16* __restrict__ pack,
                                                 u16* __restrict__ V) {
    const int t = threadIdx.x, lane = t & 63, w = t >> 6;
    const int cb = lane & 15, kq = lane >> 4;
    const int b = blockIdx.y;
    const int n0 = blockIdx.x * 192 + w * 48;
    const uint4* mp = (const uint4*)pack;

    bf16x8 af[3][2];
    #pragma unroll
    for (int mt = 0; mt < 3; ++mt) {
        int n = n0 + mt * 16 + cb;
        int nc = (n < N_) ? n : (N_ - 1);
        const float* xp = pts + b * 64 * N_ + nc;
        #pragma unroll
        for (int kk = 0; kk < 2; ++kk) {
            int jb = kk * 32 + kq * 8;
            #pragma unroll
            for (int i = 0; i < 8; ++i)
                af[mt][kk][i] = (short)f2b(xp[(size_t)(jb + i) * N_]);
        }
    }
    #pragma unroll
    for (int ct = 0; ct < 8; ++ct) {
        bf16x8 b0 = __builtin_bit_cast(bf16x8, mp[(ct * 2 + 0) * 64 + lane]);
        bf16x8 b1 = __builtin_bit_cast(bf16x8, mp[(ct * 2 + 1) * 64 + lane]);
        #pragma unroll
        for (int mt = 0; mt < 3; ++mt) {
            f32x4 acc = {};
            acc = __builtin_amdgcn_mfma_f32_16x16x32_bf16(af[mt][0], b0, acc, 0, 0, 0);
            acc = __builtin_amdgcn_mfma_f32_16x16x32_bf16(af[mt][1], b1, acc, 0, 0, 0);
            int rbase = n0 + mt * 16 + kq * 4;
            #pragma unroll
            for (int r = 0; r < 4; ++r) {
                int n = rbase + r;
                if (n < N_) V[(size_t)(b * N_ + n) * 128 + ct * 16 + cb] = f2b(acc[r]);
            }
        }
    }
}

// ---------------- P1: stats of z0, slot-based uint4 gather ----------------
__global__ __launch_bounds__(256) void p1_kernel(const u16* __restrict__ V,
                                                 const int* __restrict__ nidx,
                                                 const float* __restrict__ neg2,
                                                 float* __restrict__ stats) {
    const int t = threadIdx.x, lane = t & 63, w = t >> 6;
    const int slot = lane >> 3, cg = lane & 7;
    const int b = blockIdx.y;
    const int s0 = blockIdx.x * 384 + w * 96;
    float ngs8[8];
    #pragma unroll
    for (int i = 0; i < 8; ++i) ngs8[i] = neg2[cg * 8 + i];
    float sum[8] = {0,0,0,0,0,0,0,0}, sq[8] = {0,0,0,0,0,0,0,0};
    #pragma unroll 4
    for (int it = 0; it < 12; ++it) {
        int s = s0 + it * 8 + slot;
        int n = s / 6;
        int m = nidx[s];
        bool valid = (m < N_);
        int row2 = valid ? (b * N_ + m) : 0;
        uint4 q1 = *(const uint4*)(V + (size_t)(b * N_ + n) * 128 + cg * 8);
        uint4 q2 = *(const uint4*)(V + (size_t)row2 * 128 + 64 + cg * 8);
        float v1[8], v2[8];
        unp8(q1, v1); unp8(q2, v2);
        #pragma unroll
        for (int i = 0; i < 8; ++i) {
            float z = v1[i] + (valid ? v2[i] : ngs8[i]);
            sum[i] += z; sq[i] = fmaf(z, z, sq[i]);
        }
    }
    #pragma unroll
    for (int i = 0; i < 8; ++i) {
        sum[i] += __shfl_xor(sum[i], 8); sum[i] += __shfl_xor(sum[i], 16); sum[i] += __shfl_xor(sum[i], 32);
        sq[i]  += __shfl_xor(sq[i], 8);  sq[i]  += __shfl_xor(sq[i], 16);  sq[i]  += __shfl_xor(sq[i], 32);
    }
    __shared__ float red[2][4][64];
    if (slot == 0) {
        #pragma unroll
        for (int i = 0; i < 8; ++i) { red[0][w][cg * 8 + i] = sum[i]; red[1][w][cg * 8 + i] = sq[i]; }
    }
    __syncthreads();
    if (t < 64) {
        float s_ = (red[0][0][t] + red[0][1][t]) + (red[0][2][t] + red[0][3][t]);
        float q_ = (red[1][0][t] + red[1][1][t]) + (red[1][2][t] + red[1][3][t]);
        atomicAdd(&stats[t], s_);
        atomicAdd(&stats[64 + t], q_);
    }
}

// build A-frag with sigma row->sample permutation
__device__ inline bf16x8 build_af(const u16* __restrict__ V, int row1, int row2,
                                  const float* adt0, const float* adt1,
                                  const float* ngs, int j0) {
    float v1f[8], v2f[8];
    uint4 q1 = *(const uint4*)(V + (size_t)row1 * 128 + j0);
    unp8(q1, v1f);
    if (row2 >= 0) {
        uint4 q2 = *(const uint4*)(V + (size_t)row2 * 128 + 64 + j0);
        unp8(q2, v2f);
    } else {
        #pragma unroll
        for (int i = 0; i < 8; ++i) v2f[i] = ngs[j0 + i];
    }
    bf16x8 r;
    #pragma unroll
    for (int i = 0; i < 8; ++i) {
        float f0 = fmaxf((v1f[i] + v2f[i]) * adt0[j0 + i] + adt1[j0 + i], 0.f);
        r[i] = (short)f2b(f0);
    }
    return r;
}

// sigma: A-row (mt, cb) -> sample offset within the wave's 48 samples
__device__ inline int sigma_sl(int mt, int cb) {
    int r_ = cb & 3, kqr = cb >> 2;
    int idx = mt * 4 + r_;
    int po = (idx >= 6) ? 1 : 0;
    return (kqr * 2 + po) * 6 + (idx - 6 * po);
}

// ---------------- P2: f0 -> z1 (MFMA), stats1; optionally store z1 frags ----------------
template<int STOREZ1>
__global__ __launch_bounds__(256) void p2_kernel(const u16* __restrict__ V,
                                                 const int* __restrict__ nidx,
                                                 const float* __restrict__ neg2,
                                                 const u16* __restrict__ pack,
                                                 const float* __restrict__ g0,
                                                 const float* __restrict__ beta0,
                                                 float* __restrict__ stats,
                                                 u16* __restrict__ z1buf) {
    __shared__ float adt0[64], adt1[64], ngs[64];
    __shared__ float red[2][4][64];
    const int t = threadIdx.x, lane = t & 63, w = t >> 6;
    const int cb = lane & 15, kq = lane >> 4;
    if (t < 64) {
        float mu = stats[t] * INV_S, vr = stats[64 + t] * INV_S - mu * mu;
        float a = rsqrtf(vr + EPS_) * g0[t];
        adt0[t] = a; adt1[t] = beta0[t] - mu * a; ngs[t] = neg2[t];
    }
    __syncthreads();
    const int b = blockIdx.y;
    const int slb = blockIdx.x * 192 + w * 48;
    const uint4* w1p = (const uint4*)(pack + 8192);
    uint2* ztile = STOREZ1 ? ((uint2*)z1buf + ((size_t)b * TILES_PB + blockIdx.x * 4 + w) * (12 * 64)) : nullptr;

    bf16x8 bf[4][2];
    #pragma unroll
    for (int ct = 0; ct < 4; ++ct)
        #pragma unroll
        for (int kk = 0; kk < 2; ++kk)
            bf[ct][kk] = __builtin_bit_cast(bf16x8, w1p[(ct * 2 + kk) * 64 + lane]);

    float ssum[4] = {0,0,0,0}, ssq[4] = {0,0,0,0};
    #pragma unroll
    for (int mt = 0; mt < 3; ++mt) {
        int sl = slb + sigma_sl(mt, cb);
        int n = sl / 6;
        int m = nidx[sl];
        int row1 = b * N_ + n;
        int row2 = (m < N_) ? (b * N_ + m) : -1;
        bf16x8 af[2];
        #pragma unroll
        for (int kk = 0; kk < 2; ++kk)
            af[kk] = build_af(V, row1, row2, adt0, adt1, ngs, kk * 32 + kq * 8);
        f32x4 acc[4] = {};
        #pragma unroll
        for (int ct = 0; ct < 4; ++ct) {
            acc[ct] = __builtin_amdgcn_mfma_f32_16x16x32_bf16(af[0], bf[ct][0], acc[ct], 0, 0, 0);
            acc[ct] = __builtin_amdgcn_mfma_f32_16x16x32_bf16(af[1], bf[ct][1], acc[ct], 0, 0, 0);
        }
        #pragma unroll
        for (int ct = 0; ct < 4; ++ct) {
            #pragma unroll
            for (int r = 0; r < 4; ++r) {
                float z = acc[ct][r];
                ssum[ct] += z; ssq[ct] = fmaf(z, z, ssq[ct]);
            }
            if constexpr (STOREZ1) {
                uint lo = (uint)f2b(acc[ct][0]) | ((uint)f2b(acc[ct][1]) << 16);
                uint hi = (uint)f2b(acc[ct][2]) | ((uint)f2b(acc[ct][3]) << 16);
                ztile[(mt * 4 + ct) * 64 + lane] = {lo, hi};
            }
        }
    }
    #pragma unroll
    for (int ct = 0; ct < 4; ++ct) {
        ssum[ct] += __shfl_xor(ssum[ct], 16); ssum[ct] += __shfl_xor(ssum[ct], 32);
        ssq[ct]  += __shfl_xor(ssq[ct], 16);  ssq[ct]  += __shfl_xor(ssq[ct], 32);
    }
    if (lane < 16) {
        #pragma unroll
        for (int ct = 0; ct < 4; ++ct) {
            red[0][w][ct * 16 + lane] = ssum[ct];
            red[1][w][ct * 16 + lane] = ssq[ct];
        }
    }
    __syncthreads();
    if (t < 64) {
        float s = (red[0][0][t] + red[0][1][t]) + (red[0][2][t] + red[0][3][t]);
        float q = (red[1][0][t] + red[1][1][t]) + (red[1][2][t] + red[1][3][t]);
        atomicAdd(&stats[128 + t], s);
        atomicAdd(&stats[192 + t], q);
    }
}

// ---------------- P3: z1 -> f1 -> z2 (MFMA), stats2, register k-max via sigma ----------------
template<int LOADZ1>
__global__ __launch_bounds__(256) void p3_kernel(const u16* __restrict__ V,
                                                 const int* __restrict__ nidx,
                                                 const float* __restrict__ neg2,
                                                 const u16* __restrict__ pack,
                                                 const float* __restrict__ g0, const float* __restrict__ beta0,
                                                 const float* __restrict__ g1, const float* __restrict__ beta1,
                                                 const float* __restrict__ g2,
                                                 float* __restrict__ stats,
                                                 const u16* __restrict__ z1buf,
                                                 float* __restrict__ out) {
    __shared__ u16   f1t[4][16 * 64];        // per-wave 16x64 bf16, XOR-swizzled, reused per mt
    __shared__ float smax[32][129];          // per-point sign-adjusted max (exclusive writes)
    __shared__ float red[2][4][128];
    __shared__ float adt2s[64], adt3s[64], psign[128];
    __shared__ float adt0s[64], adt1s[64], ngs[64];   // only used when !LOADZ1
    const int t = threadIdx.x, lane = t & 63, w = t >> 6;
    const int cb = lane & 15, kq = lane >> 4;
    if (t < 64) {
        float mu1 = stats[128 + t] * INV_S, vr1 = stats[192 + t] * INV_S - mu1 * mu1;
        float a1 = rsqrtf(vr1 + EPS_) * g1[t];
        adt2s[t] = a1; adt3s[t] = beta1[t] - mu1 * a1;
        if constexpr (!LOADZ1) {
            float mu0 = stats[t] * INV_S, vr0 = stats[64 + t] * INV_S - mu0 * mu0;
            float a0 = rsqrtf(vr0 + EPS_) * g0[t];
            adt0s[t] = a0; adt1s[t] = beta0[t] - mu0 * a0; ngs[t] = neg2[t];
        }
    }
    if (t < 128) psign[t] = (g2[t] >= 0.f) ? 1.f : -1.f;
    __syncthreads();

    const int b = blockIdx.y;
    const int slb = blockIdx.x * 192 + w * 48;
    const uint4* w1p = (const uint4*)(pack + 8192);
    const uint4* w2p = (const uint4*)(pack + 12288);
    const uint2* zt = LOADZ1 ? ((const uint2*)z1buf + ((size_t)b * TILES_PB + blockIdx.x * 4 + w) * (12 * 64)) : nullptr;

    bf16x8 bf2[8][2];
    #pragma unroll
    for (int u = 0; u < 8; ++u)
        #pragma unroll
        for (int kk = 0; kk < 2; ++kk)
            bf2[u][kk] = __builtin_bit_cast(bf16x8, w2p[(u * 2 + kk) * 64 + lane]);

    float a1c[4], d1c[4];
    #pragma unroll
    for (int ct = 0; ct < 4; ++ct) { a1c[ct] = adt2s[ct * 16 + cb]; d1c[ct] = adt3s[ct * 16 + cb]; }

    float pmax_[2][4][2];
    #pragma unroll
    for (int h = 0; h < 2; ++h)
        #pragma unroll
        for (int ct = 0; ct < 4; ++ct) { pmax_[h][ct][0] = -3.402823466e+38f; pmax_[h][ct][1] = -3.402823466e+38f; }
    float ssum[8] = {0,0,0,0,0,0,0,0}, ssq[8] = {0,0,0,0,0,0,0,0};
    u16* fb = f1t[w];

    #pragma unroll
    for (int mt = 0; mt < 3; ++mt) {
        f32x4 z1v[4];
        if constexpr (LOADZ1) {
            #pragma unroll
            for (int ct = 0; ct < 4; ++ct) {
                uint2 q = zt[(mt * 4 + ct) * 64 + lane];
                z1v[ct][0] = b2f_lo(q.x); z1v[ct][1] = b2f_hi(q.x);
                z1v[ct][2] = b2f_lo(q.y); z1v[ct][3] = b2f_hi(q.y);
            }
        } else {
            bf16x8 bf1[4][2];
            #pragma unroll
            for (int ct = 0; ct < 4; ++ct)
                #pragma unroll
                for (int kk = 0; kk < 2; ++kk)
                    bf1[ct][kk] = __builtin_bit_cast(bf16x8, w1p[(ct * 2 + kk) * 64 + lane]);
            int sl = slb + sigma_sl(mt, cb);
            int n = sl / 6;
            int m = nidx[sl];
            int row1 = b * N_ + n;
            int row2 = (m < N_) ? (b * N_ + m) : -1;
            bf16x8 af[2];
            #pragma unroll
            for (int kk = 0; kk < 2; ++kk)
                af[kk] = build_af(V, row1, row2, adt0s, adt1s, ngs, kk * 32 + kq * 8);
            #pragma unroll
            for (int ct = 0; ct < 4; ++ct) {
                f32x4 a = {};
                a = __builtin_amdgcn_mfma_f32_16x16x32_bf16(af[0], bf1[ct][0], a, 0, 0, 0);
                a = __builtin_amdgcn_mfma_f32_16x16x32_bf16(af[1], bf1[ct][1], a, 0, 0, 0);
                z1v[ct] = a;
            }
        }
        // BN1 + ReLU -> f1 tile (rows kq*4+r, cols ct*16+cb, XOR-swizzled)
        #pragma unroll
        for (int ct = 0; ct < 4; ++ct) {
            #pragma unroll
            for (int r = 0; r < 4; ++r) {
                float f1 = fmaxf(z1v[ct][r] * a1c[ct] + d1c[ct], 0.f);
                int rw = kq * 4 + r;
                fb[rw * 64 + ((ct * 16 + cb) ^ ((rw & 7) << 3))] = f2b(f1);
            }
        }
        // read back-A frags (row cb)
        bf16x8 af2[2];
        #pragma unroll
        for (int kk = 0; kk < 2; ++kk) {
            int j0 = kk * 32 + kq * 8;
            af2[kk] = __builtin_bit_cast(bf16x8, *(const uint4*)(fb + cb * 64 + (j0 ^ ((cb & 7) << 3))));
        }
        #pragma unroll
        for (int half = 0; half < 2; ++half) {
            f32x4 acc2[4] = {};
            #pragma unroll
            for (int ct = 0; ct < 4; ++ct) {
                acc2[ct] = __builtin_amdgcn_mfma_f32_16x16x32_bf16(af2[0], bf2[half * 4 + ct][0], acc2[ct], 0, 0, 0);
                acc2[ct] = __builtin_amdgcn_mfma_f32_16x16x32_bf16(af2[1], bf2[half * 4 + ct][1], acc2[ct], 0, 0, 0);
            }
            #pragma unroll
            for (int ct = 0; ct < 4; ++ct) {
                float ps = psign[half * 64 + ct * 16 + cb];
                #pragma unroll
                for (int r = 0; r < 4; ++r) {
                    float z = acc2[ct][r];
                    ssum[half * 4 + ct] += z;
                    ssq[half * 4 + ct] = fmaf(z, z, ssq[half * 4 + ct]);
                    float zz = z * ps;
                    int pi = (mt == 0) ? 0 : ((mt == 2) ? 1 : ((r >= 2) ? 1 : 0));
                    pmax_[half][ct][pi] = fmaxf(pmax_[half][ct][pi], zz);
                }
            }
        }
    }
    // exclusive smax writes: lane owns points kq*2, kq*2+1 of its wave
    #pragma unroll
    for (int half = 0; half < 2; ++half)
        #pragma unroll
        for (int ct = 0; ct < 4; ++ct)
            #pragma unroll
            for (int p = 0; p < 2; ++p)
                smax[w * 8 + kq * 2 + p][half * 64 + ct * 16 + cb] = pmax_[half][ct][p];
    // stats2 reduce
    #pragma unroll
    for (int j = 0; j < 8; ++j) {
        ssum[j] += __shfl_xor(ssum[j], 16); ssum[j] += __shfl_xor(ssum[j], 32);
        ssq[j]  += __shfl_xor(ssq[j], 16);  ssq[j]  += __shfl_xor(ssq[j], 32);
    }
    if (lane < 16) {
        #pragma unroll
        for (int j = 0; j < 8; ++j) {
            int c = (j >> 2) * 64 + (j & 3) * 16 + lane;
            red[0][w][c] = ssum[j];
            red[1][w][c] = ssq[j];
        }
    }
    __syncthreads();
    if (t < 128) {
        float s = (red[0][0][t] + red[0][1][t]) + (red[0][2][t] + red[0][3][t]);
        float q = (red[1][0][t] + red[1][1][t]) + (red[1][2][t] + red[1][3][t]);
        atomicAdd(&stats[256 + t], s);
        atomicAdd(&stats[384 + t], q);
    }
    // coalesced raw sign-max write: out[b][c2][n0..n0+31]
    {
        int c2 = t >> 1, nh = t & 1;
        float ps = psign[c2];
        float* op = out + OF_ + ((size_t)b * 128 + c2) * N_ + blockIdx.x * 32 + nh * 16;
        #pragma unroll
        for (int i4 = 0; i4 < 4; ++i4) {
            float4 v;
            v.x = smax[nh * 16 + i4 * 4 + 0][c2] * ps;
            v.y = smax[nh * 16 + i4 * 4 + 1][c2] * ps;
            v.z = smax[nh * 16 + i4 * 4 + 2][c2] * ps;
            v.w = smax[nh * 16 + i4 * 4 + 3][c2] * ps;
            *(float4*)(op + i4 * 4) = v;
        }
    }
}

// ---------------- P4: normalize new_feature in place + channel max ----------------
__global__ __launch_bounds__(256) void p4_kernel(const float* __restrict__ g2,
                                                 const float* __restrict__ beta2,
                                                 const float* __restrict__ stats,
                                                 float* __restrict__ outbuf) {
    __shared__ float a2s[128], d2s[128];
    const int t = threadIdx.x;
    if (t < 128) {
        float mu = stats[256 + t] * INV_S;
        float vr = stats[384 + t] * INV_S - mu * mu;
        float a = rsqrtf(vr + EPS_) * g2[t];
        a2s[t] = a;
        d2s[t] = beta2[t] - mu * a;
    }
    __syncthreads();
    const int b = blockIdx.y;
    const int n = blockIdx.x * 256 + t;
    if (n >= N_) return;
    float vmax = -3.402823466e+38f;
    #pragma unroll 8
    for (int c2 = 0; c2 < 128; ++c2) {
        size_t idx = OF_ + ((size_t)b * 128 + c2) * N_ + n;
        float v = fmaxf(outbuf[idx] * a2s[c2] + d2s[c2], 0.f);
        outbuf[idx] = v;
        vmax = fmaxf(vmax, v);
    }
    outbuf[b * N_ + n] = vmax;
}

extern "C" void kernel_launch(void* const* d_in, const int* in_sizes, int n_in,
                              void* d_out, int out_size, void* d_ws, size_t ws_size,
                              hipStream_t stream) {
    (void)in_sizes; (void)n_in; (void)out_size;
    const float* pts   = (const float*)d_in[0];
    const int*   nidx  = (const int*)d_in[1];
    const float* W0    = (const float*)d_in[2];
    const float* g0    = (const float*)d_in[4];
    const float* beta0 = (const float*)d_in[5];
    const float* W1    = (const float*)d_in[6];
    const float* g1    = (const float*)d_in[8];
    const float* beta1 = (const float*)d_in[9];
    const float* W2    = (const float*)d_in[10];
    const float* g2    = (const float*)d_in[12];
    const float* beta2 = (const float*)d_in[13];
    const bool big = ws_size >= NEED_BIG_B;   // deterministic per-session branch
    u16*   V     = (u16*)d_ws;
    u16*   z1b   = big ? ((u16*)d_ws + WS_V_U16) : nullptr;
    float* stats = (float*)d_ws + (big ? 20480000 : 5120000);
    float* neg2  = stats + 512;
    u16*   pack  = (u16*)d_ws + (big ? 40961152 : 10241152);
    float* out   = (float*)d_out;

    hipLaunchKernelGGL(wprep_kernel, dim3(1), dim3(256), 0, stream, W0, W1, W2, stats, neg2, pack);
    hipLaunchKernelGGL(p0_kernel, dim3((N_ + 191) / 192, B_), dim3(256), 0, stream, pts, pack, V);
    hipLaunchKernelGGL(p1_kernel, dim3(SPB / 384, B_), dim3(256), 0, stream, V, nidx, neg2, stats);
    if (big) {
        hipLaunchKernelGGL((p2_kernel<1>), dim3(SPB / 192, B_), dim3(256), 0, stream,
                           V, nidx, neg2, pack, g0, beta0, stats, z1b);
        hipLaunchKernelGGL((p3_kernel<1>), dim3(SPB / 192, B_), dim3(256), 0, stream,
                           V, nidx, neg2, pack, g0, beta0, g1, beta1, g2, stats, z1b, out);
    } else {
        hipLaunchKernelGGL((p2_kernel<0>), dim3(SPB / 192, B_), dim3(256), 0, stream,
                           V, nidx, neg2, pack, g0, beta0, stats, z1b);
        hipLaunchKernelGGL((p3_kernel<0>), dim3(SPB / 192, B_), dim3(256), 0, stream,
                           V, nidx, neg2, pack, g0, beta0, g1, beta1, g2, stats, z1b, out);
    }
    hipLaunchKernelGGL(p4_kernel, dim3((N_ + 255) / 256, B_), dim3(256), 0, stream, g2, beta2, stats, out);
}

// Round 7
// 298.490 us; speedup vs baseline: 3.1083x; 1.0354x over previous
//
#include <hip/hip_runtime.h>

typedef unsigned short u16;
typedef unsigned int uint;
typedef short bf16x8 __attribute__((ext_vector_type(8)));
typedef float f32x4 __attribute__((ext_vector_type(4)));

constexpr int B_ = 2;
constexpr int N_ = 40000;
constexpr int SPB = 240000;            // samples per batch = N*6
constexpr int S_ = B_ * SPB;           // 480000 BN samples
constexpr float EPS_ = 1e-5f;
constexpr float INV_S = 1.0f / (float)S_;
constexpr int OF_ = B_ * N_;           // out_feature elems before new_feature
constexpr int TILES_PB = SPB / 48;     // 5000 wave-tiles per batch

// ws (u16 units): V bf16 [B*N][128] @0 (=raw-max region for p3big/p4big, V dead by then)
//   big: z1 @10,240,000..40,960,000; stats f32@u16 40,960,000; neg2; pack u16@40,961,152
//   small: stats f32@u16 10,240,000; pack u16@10,241,152
constexpr int      WS_V_U16   = B_ * N_ * 128;
constexpr size_t   NEED_BIG_B = 81955072ull;

// ---------- helpers ----------
__device__ inline float b2f_lo(uint u) { return __builtin_bit_cast(float, u << 16); }
__device__ inline float b2f_hi(uint u) { return __builtin_bit_cast(float, u & 0xffff0000u); }
__device__ inline float b2fu(u16 s)    { return __builtin_bit_cast(float, ((uint)s) << 16); }
__device__ inline u16 f2b(float f) {   // RNE float->bf16
    uint b = __builtin_bit_cast(uint, f);
    return (u16)((b + 0x7fffu + ((b >> 16) & 1u)) >> 16);
}
__device__ inline uint pk2(float a, float b) { return (uint)f2b(a) | ((uint)f2b(b) << 16); }
__device__ inline void unp8(uint4 q, float* f) {
    f[0] = b2f_lo(q.x); f[1] = b2f_hi(q.x); f[2] = b2f_lo(q.y); f[3] = b2f_hi(q.y);
    f[4] = b2f_lo(q.z); f[5] = b2f_hi(q.z); f[6] = b2f_lo(q.w); f[7] = b2f_hi(q.w);
}

// ---------------- WPREP ----------------
__global__ __launch_bounds__(256) void wprep_kernel(const float* __restrict__ W0,
                                                    const float* __restrict__ W1,
                                                    const float* __restrict__ W2,
                                                    float* __restrict__ stats,
                                                    float* __restrict__ neg2,
                                                    u16* __restrict__ pack) {
    const int t = threadIdx.x;
    stats[t] = 0.f; stats[t + 256] = 0.f;
    if (t < 64) {
        float s = 0.f;
        for (int j = 0; j < 64; ++j) s += W0[t * 128 + 64 + j];
        neg2[t] = -s;
    }
    for (int g = t; g < 40 * 64; g += 256) {
        int lane = g & 63, grp = g >> 6;
        int cb = lane & 15, kq = lane >> 4;
        ushort4 lo, hi;
        u16* dst;
        if (grp < 16) {
            int ct = grp >> 1, kk = grp & 1;
            int c = ct * 16 + cb, jb = kk * 32 + kq * 8;
            dst = pack + g * 8;
            float v[8];
            #pragma unroll
            for (int i = 0; i < 8; ++i)
                v[i] = (c < 64) ? W0[c * 128 + jb + i] : W0[(c - 64) * 128 + 64 + jb + i];
            lo = {f2b(v[0]), f2b(v[1]), f2b(v[2]), f2b(v[3])};
            hi = {f2b(v[4]), f2b(v[5]), f2b(v[6]), f2b(v[7])};
        } else if (grp < 24) {
            int g2 = grp - 16;
            int ct = g2 >> 1, kk = g2 & 1;
            const float* wp = W1 + (ct * 16 + cb) * 64 + kk * 32 + kq * 8;
            dst = pack + 8192 + (g2 * 64 + lane) * 8;
            lo = {f2b(wp[0]), f2b(wp[1]), f2b(wp[2]), f2b(wp[3])};
            hi = {f2b(wp[4]), f2b(wp[5]), f2b(wp[6]), f2b(wp[7])};
        } else {
            int g3 = grp - 24;
            int ct = g3 >> 1, kk = g3 & 1;
            const float* wp = W2 + (ct * 16 + cb) * 64 + kk * 32 + kq * 8;
            dst = pack + 12288 + (g3 * 64 + lane) * 8;
            lo = {f2b(wp[0]), f2b(wp[1]), f2b(wp[2]), f2b(wp[3])};
            hi = {f2b(wp[4]), f2b(wp[5]), f2b(wp[6]), f2b(wp[7])};
        }
        *(ushort4*)dst = lo;
        *(ushort4*)(dst + 4) = hi;
    }
}

// ---------------- P0 (MFMA): V = M @ x ----------------
__global__ __launch_bounds__(256) void p0_kernel(const float* __restrict__ pts,
                                                 const u16* __restrict__ pack,
                                                 u16* __restrict__ V) {
    const int t = threadIdx.x, lane = t & 63, w = t >> 6;
    const int cb = lane & 15, kq = lane >> 4;
    const int b = blockIdx.y;
    const int n0 = blockIdx.x * 192 + w * 48;
    const uint4* mp = (const uint4*)pack;

    bf16x8 af[3][2];
    #pragma unroll
    for (int mt = 0; mt < 3; ++mt) {
        int n = n0 + mt * 16 + cb;
        int nc = (n < N_) ? n : (N_ - 1);
        const float* xp = pts + b * 64 * N_ + nc;
        #pragma unroll
        for (int kk = 0; kk < 2; ++kk) {
            int jb = kk * 32 + kq * 8;
            #pragma unroll
            for (int i = 0; i < 8; ++i)
                af[mt][kk][i] = (short)f2b(xp[(size_t)(jb + i) * N_]);
        }
    }
    #pragma unroll
    for (int ct = 0; ct < 8; ++ct) {
        bf16x8 b0 = __builtin_bit_cast(bf16x8, mp[(ct * 2 + 0) * 64 + lane]);
        bf16x8 b1 = __builtin_bit_cast(bf16x8, mp[(ct * 2 + 1) * 64 + lane]);
        #pragma unroll
        for (int mt = 0; mt < 3; ++mt) {
            f32x4 acc = {};
            acc = __builtin_amdgcn_mfma_f32_16x16x32_bf16(af[mt][0], b0, acc, 0, 0, 0);
            acc = __builtin_amdgcn_mfma_f32_16x16x32_bf16(af[mt][1], b1, acc, 0, 0, 0);
            int rbase = n0 + mt * 16 + kq * 4;
            #pragma unroll
            for (int r = 0; r < 4; ++r) {
                int n = rbase + r;
                if (n < N_) V[(size_t)(b * N_ + n) * 128 + ct * 16 + cb] = f2b(acc[r]);
            }
        }
    }
}

// ---------------- P1: stats of z0, hoisted-batch gather ----------------
__global__ __launch_bounds__(256) void p1_kernel(const u16* __restrict__ V,
                                                 const int* __restrict__ nidx,
                                                 const float* __restrict__ neg2,
                                                 float* __restrict__ stats) {
    const int t = threadIdx.x, lane = t & 63, w = t >> 6;
    const int slot = lane >> 3, cg = lane & 7;
    const int b = blockIdx.y;
    const int s0 = blockIdx.x * 384 + w * 96;
    float ngs8[8];
    #pragma unroll
    for (int i = 0; i < 8; ++i) ngs8[i] = neg2[cg * 8 + i];
    float sum[8] = {0,0,0,0,0,0,0,0}, sq[8] = {0,0,0,0,0,0,0,0};
    #pragma unroll
    for (int h = 0; h < 2; ++h) {
        int mh[6]; uint4 q1[6], q2[6]; bool val[6];
        #pragma unroll
        for (int it = 0; it < 6; ++it) {
            int s = s0 + (h * 6 + it) * 8 + slot;
            mh[it] = nidx[s];
            q1[it] = *(const uint4*)(V + (size_t)(b * N_ + s / 6) * 128 + cg * 8);
        }
        #pragma unroll
        for (int it = 0; it < 6; ++it) {
            val[it] = (mh[it] < N_);
            int row2 = val[it] ? (b * N_ + mh[it]) : 0;
            q2[it] = *(const uint4*)(V + (size_t)row2 * 128 + 64 + cg * 8);
        }
        #pragma unroll
        for (int it = 0; it < 6; ++it) {
            float v1[8], v2[8];
            unp8(q1[it], v1); unp8(q2[it], v2);
            #pragma unroll
            for (int i = 0; i < 8; ++i) {
                float z = v1[i] + (val[it] ? v2[i] : ngs8[i]);
                sum[i] += z; sq[i] = fmaf(z, z, sq[i]);
            }
        }
    }
    #pragma unroll
    for (int i = 0; i < 8; ++i) {
        sum[i] += __shfl_xor(sum[i], 8); sum[i] += __shfl_xor(sum[i], 16); sum[i] += __shfl_xor(sum[i], 32);
        sq[i]  += __shfl_xor(sq[i], 8);  sq[i]  += __shfl_xor(sq[i], 16);  sq[i]  += __shfl_xor(sq[i], 32);
    }
    __shared__ float red[2][4][64];
    if (slot == 0) {
        #pragma unroll
        for (int i = 0; i < 8; ++i) { red[0][w][cg * 8 + i] = sum[i]; red[1][w][cg * 8 + i] = sq[i]; }
    }
    __syncthreads();
    if (t < 64) {
        float s_ = (red[0][0][t] + red[0][1][t]) + (red[0][2][t] + red[0][3][t]);
        float q_ = (red[1][0][t] + red[1][1][t]) + (red[1][2][t] + red[1][3][t]);
        atomicAdd(&stats[t], s_);
        atomicAdd(&stats[64 + t], q_);
    }
}

// build A-frag
__device__ inline bf16x8 build_af(const u16* __restrict__ V, int row1, int row2,
                                  const float* adt0, const float* adt1,
                                  const float* ngs, int j0) {
    float v1f[8], v2f[8];
    uint4 q1 = *(const uint4*)(V + (size_t)row1 * 128 + j0);
    unp8(q1, v1f);
    if (row2 >= 0) {
        uint4 q2 = *(const uint4*)(V + (size_t)row2 * 128 + 64 + j0);
        unp8(q2, v2f);
    } else {
        #pragma unroll
        for (int i = 0; i < 8; ++i) v2f[i] = ngs[j0 + i];
    }
    bf16x8 r;
    #pragma unroll
    for (int i = 0; i < 8; ++i) {
        float f0 = fmaxf((v1f[i] + v2f[i]) * adt0[j0 + i] + adt1[j0 + i], 0.f);
        r[i] = (short)f2b(f0);
    }
    return r;
}

// sigma: A-row (mt, row) -> sample offset within wave's 48 samples
__device__ inline int sigma_sl(int mt, int row) {
    int r_ = row & 3, kqr = row >> 2;
    int idx = mt * 4 + r_;
    int po = (idx >= 6) ? 1 : 0;
    return (kqr * 2 + po) * 6 + (idx - 6 * po);
}

// ---------------- P2: f0 -> z1 (MFMA), stats1; optionally store z1 (paired-uint4 layout) ----------------
template<int STOREZ1>
__global__ __launch_bounds__(256) void p2_kernel(const u16* __restrict__ V,
                                                 const int* __restrict__ nidx,
                                                 const float* __restrict__ neg2,
                                                 const u16* __restrict__ pack,
                                                 const float* __restrict__ g0,
                                                 const float* __restrict__ beta0,
                                                 float* __restrict__ stats,
                                                 u16* __restrict__ z1buf) {
    __shared__ float adt0[64], adt1[64], ngs[64];
    __shared__ float red[2][4][64];
    const int t = threadIdx.x, lane = t & 63, w = t >> 6;
    const int cb = lane & 15, kq = lane >> 4;
    if (t < 64) {
        float mu = stats[t] * INV_S, vr = stats[64 + t] * INV_S - mu * mu;
        float a = rsqrtf(vr + EPS_) * g0[t];
        adt0[t] = a; adt1[t] = beta0[t] - mu * a; ngs[t] = neg2[t];
    }
    __syncthreads();
    const int b = blockIdx.y;
    const int slb = blockIdx.x * 192 + w * 48;
    const uint4* w1p = (const uint4*)(pack + 8192);
    uint4* zt4 = STOREZ1 ? ((uint4*)z1buf + ((size_t)b * TILES_PB + blockIdx.x * 4 + w) * (6 * 64)) : nullptr;

    int m_[3];
    #pragma unroll
    for (int mt = 0; mt < 3; ++mt) m_[mt] = nidx[slb + sigma_sl(mt, cb)];

    bf16x8 bf[4][2];
    #pragma unroll
    for (int ct = 0; ct < 4; ++ct)
        #pragma unroll
        for (int kk = 0; kk < 2; ++kk)
            bf[ct][kk] = __builtin_bit_cast(bf16x8, w1p[(ct * 2 + kk) * 64 + lane]);

    float ssum[4] = {0,0,0,0}, ssq[4] = {0,0,0,0};
    #pragma unroll
    for (int mt = 0; mt < 3; ++mt) {
        int sl = slb + sigma_sl(mt, cb);
        int n = sl / 6;
        int row1 = b * N_ + n;
        int row2 = (m_[mt] < N_) ? (b * N_ + m_[mt]) : -1;
        bf16x8 af[2];
        #pragma unroll
        for (int kk = 0; kk < 2; ++kk)
            af[kk] = build_af(V, row1, row2, adt0, adt1, ngs, kk * 32 + kq * 8);
        f32x4 acc[4] = {};
        #pragma unroll
        for (int ct = 0; ct < 4; ++ct) {
            acc[ct] = __builtin_amdgcn_mfma_f32_16x16x32_bf16(af[0], bf[ct][0], acc[ct], 0, 0, 0);
            acc[ct] = __builtin_amdgcn_mfma_f32_16x16x32_bf16(af[1], bf[ct][1], acc[ct], 0, 0, 0);
        }
        #pragma unroll
        for (int ct = 0; ct < 4; ++ct)
            #pragma unroll
            for (int r = 0; r < 4; ++r) {
                float z = acc[ct][r];
                ssum[ct] += z; ssq[ct] = fmaf(z, z, ssq[ct]);
            }
        if constexpr (STOREZ1) {
            #pragma unroll
            for (int cp = 0; cp < 2; ++cp) {
                uint4 o;
                o.x = pk2(acc[cp * 2][0], acc[cp * 2][1]);
                o.y = pk2(acc[cp * 2][2], acc[cp * 2][3]);
                o.z = pk2(acc[cp * 2 + 1][0], acc[cp * 2 + 1][1]);
                o.w = pk2(acc[cp * 2 + 1][2], acc[cp * 2 + 1][3]);
                zt4[(mt * 2 + cp) * 64 + lane] = o;
            }
        }
    }
    #pragma unroll
    for (int ct = 0; ct < 4; ++ct) {
        ssum[ct] += __shfl_xor(ssum[ct], 16); ssum[ct] += __shfl_xor(ssum[ct], 32);
        ssq[ct]  += __shfl_xor(ssq[ct], 16);  ssq[ct]  += __shfl_xor(ssq[ct], 32);
    }
    if (lane < 16) {
        #pragma unroll
        for (int ct = 0; ct < 4; ++ct) {
            red[0][w][ct * 16 + lane] = ssum[ct];
            red[1][w][ct * 16 + lane] = ssq[ct];
        }
    }
    __syncthreads();
    if (t < 64) {
        float s = (red[0][0][t] + red[0][1][t]) + (red[0][2][t] + red[0][3][t]);
        float q = (red[1][0][t] + red[1][1][t]) + (red[1][2][t] + red[1][3][t]);
        atomicAdd(&stats[128 + t], s);
        atomicAdd(&stats[192 + t], q);
    }
}

// ---------------- P3 big: z1 -> f1 -> z2, dbuf-pipelined, bf16 raw max into V region ----------------
__global__ __launch_bounds__(256) void p3big_kernel(const u16* __restrict__ z1buf,
                                                    const u16* __restrict__ pack,
                                                    const float* __restrict__ g1, const float* __restrict__ beta1,
                                                    const float* __restrict__ g2,
                                                    float* __restrict__ stats,
                                                    u16* __restrict__ raw) {
    __shared__ u16   f1t[4][2][1024];        // per-wave double-buffered 16x64 bf16, XOR-swizzled
    __shared__ float smax[32][129];
    __shared__ float red[2][4][128];
    __shared__ float adt2s[64], adt3s[64], psign[128];
    const int t = threadIdx.x, lane = t & 63, w = t >> 6;
    const int cb = lane & 15, kq = lane >> 4;
    if (t < 64) {
        float mu1 = stats[128 + t] * INV_S, vr1 = stats[192 + t] * INV_S - mu1 * mu1;
        float a1 = rsqrtf(vr1 + EPS_) * g1[t];
        adt2s[t] = a1; adt3s[t] = beta1[t] - mu1 * a1;
    }
    if (t < 128) psign[t] = (g2[t] >= 0.f) ? 1.f : -1.f;
    __syncthreads();

    const int b = blockIdx.y;
    const uint4* zt4 = (const uint4*)z1buf + ((size_t)b * TILES_PB + blockIdx.x * 4 + w) * (6 * 64);
    const uint4* w2p = (const uint4*)(pack + 12288);

    uint4 zq[6];
    #pragma unroll
    for (int i = 0; i < 6; ++i) zq[i] = zt4[i * 64 + lane];

    bf16x8 bf2[8][2];
    #pragma unroll
    for (int u = 0; u < 8; ++u)
        #pragma unroll
        for (int kk = 0; kk < 2; ++kk)
            bf2[u][kk] = __builtin_bit_cast(bf16x8, w2p[(u * 2 + kk) * 64 + lane]);

    float a1c[4], d1c[4];
    #pragma unroll
    for (int ct = 0; ct < 4; ++ct) { a1c[ct] = adt2s[ct * 16 + cb]; d1c[ct] = adt3s[ct * 16 + cb]; }

    float pmax_[2][4][2];
    #pragma unroll
    for (int h = 0; h < 2; ++h)
        #pragma unroll
        for (int ct = 0; ct < 4; ++ct) { pmax_[h][ct][0] = -3.402823466e+38f; pmax_[h][ct][1] = -3.402823466e+38f; }
    float ssum[8] = {0,0,0,0,0,0,0,0}, ssq[8] = {0,0,0,0,0,0,0,0};
    u16* fb0 = f1t[w][0];
    u16* fb1 = f1t[w][1];

    // BN1 + relu + swizzled write of tile mt into fb
    auto BNW = [&](int mt, u16* fb) {
        #pragma unroll
        for (int cp = 0; cp < 2; ++cp) {
            uint4 q = zq[mt * 2 + cp];
            float za[4] = {b2f_lo(q.x), b2f_hi(q.x), b2f_lo(q.y), b2f_hi(q.y)};
            float zb[4] = {b2f_lo(q.z), b2f_hi(q.z), b2f_lo(q.w), b2f_hi(q.w)};
            int ca = cp * 2, cc = cp * 2 + 1;
            #pragma unroll
            for (int r = 0; r < 4; ++r) {
                int rw = kq * 4 + r;
                fb[rw * 64 + ((ca * 16 + cb) ^ ((rw & 7) << 3))] = f2b(fmaxf(za[r] * a1c[ca] + d1c[ca], 0.f));
                fb[rw * 64 + ((cc * 16 + cb) ^ ((rw & 7) << 3))] = f2b(fmaxf(zb[r] * a1c[cc] + d1c[cc], 0.f));
            }
        }
    };
    auto RDA = [&](const u16* fb, bf16x8* af2) {
        #pragma unroll
        for (int kk = 0; kk < 2; ++kk) {
            int j0 = kk * 32 + kq * 8;
            af2[kk] = __builtin_bit_cast(bf16x8, *(const uint4*)(fb + cb * 64 + (j0 ^ ((cb & 7) << 3))));
        }
    };
    auto MM = [&](int mt, const bf16x8* af2) {
        #pragma unroll
        for (int half = 0; half < 2; ++half) {
            f32x4 acc2[4] = {};
            #pragma unroll
            for (int ct = 0; ct < 4; ++ct) {
                acc2[ct] = __builtin_amdgcn_mfma_f32_16x16x32_bf16(af2[0], bf2[half * 4 + ct][0], acc2[ct], 0, 0, 0);
                acc2[ct] = __builtin_amdgcn_mfma_f32_16x16x32_bf16(af2[1], bf2[half * 4 + ct][1], acc2[ct], 0, 0, 0);
            }
            #pragma unroll
            for (int ct = 0; ct < 4; ++ct) {
                float ps = psign[half * 64 + ct * 16 + cb];
                #pragma unroll
                for (int r = 0; r < 4; ++r) {
                    float z = acc2[ct][r];
                    ssum[half * 4 + ct] += z;
                    ssq[half * 4 + ct] = fmaf(z, z, ssq[half * 4 + ct]);
                    float zz = z * ps;
                    int pi = (mt == 0) ? 0 : ((mt == 2) ? 1 : ((r >= 2) ? 1 : 0));
                    pmax_[half][ct][pi] = fmaxf(pmax_[half][ct][pi], zz);
                }
            }
        }
    };

    bf16x8 afA[2], afB[2];
    BNW(0, fb0); BNW(1, fb1);
    RDA(fb0, afA);
    MM(0, afA);
    BNW(2, fb0);           // WAR on fb0 is safe: per-wave DS ops are in-order
    RDA(fb1, afB);
    MM(1, afB);
    RDA(fb0, afA);
    MM(2, afA);

    #pragma unroll
    for (int half = 0; half < 2; ++half)
        #pragma unroll
        for (int ct = 0; ct < 4; ++ct)
            #pragma unroll
            for (int p = 0; p < 2; ++p)
                smax[w * 8 + kq * 2 + p][half * 64 + ct * 16 + cb] = pmax_[half][ct][p];
    #pragma unroll
    for (int j = 0; j < 8; ++j) {
        ssum[j] += __shfl_xor(ssum[j], 16); ssum[j] += __shfl_xor(ssum[j], 32);
        ssq[j]  += __shfl_xor(ssq[j], 16);  ssq[j]  += __shfl_xor(ssq[j], 32);
    }
    if (lane < 16) {
        #pragma unroll
        for (int j = 0; j < 8; ++j) {
            int c = (j >> 2) * 64 + (j & 3) * 16 + lane;
            red[0][w][c] = ssum[j];
            red[1][w][c] = ssq[j];
        }
    }
    __syncthreads();
    if (t < 128) {
        float s = (red[0][0][t] + red[0][1][t]) + (red[0][2][t] + red[0][3][t]);
        float q = (red[1][0][t] + red[1][1][t]) + (red[1][2][t] + red[1][3][t]);
        atomicAdd(&stats[256 + t], s);
        atomicAdd(&stats[384 + t], q);
    }
    // raw sign-max (bf16) -> raw[b][c2][n0..n0+31]
    {
        int c2 = t >> 1, nh = t & 1;
        float ps = psign[c2];
        u16* rp = raw + ((size_t)b * 128 + c2) * N_ + blockIdx.x * 32 + nh * 16;
        #pragma unroll
        for (int i4 = 0; i4 < 4; ++i4) {
            ushort4 v;
            v.x = f2b(smax[nh * 16 + i4 * 4 + 0][c2] * ps);
            v.y = f2b(smax[nh * 16 + i4 * 4 + 1][c2] * ps);
            v.z = f2b(smax[nh * 16 + i4 * 4 + 2][c2] * ps);
            v.w = f2b(smax[nh * 16 + i4 * 4 + 3][c2] * ps);
            *(ushort4*)(rp + i4 * 4) = v;
        }
    }
}

// ---------------- P3 small (recompute path, f32 raw to out) — round-6 logic ----------------
__global__ __launch_bounds__(256) void p3small_kernel(const u16* __restrict__ V,
                                                      const int* __restrict__ nidx,
                                                      const float* __restrict__ neg2,
                                                      const u16* __restrict__ pack,
                                                      const float* __restrict__ g0, const float* __restrict__ beta0,
                                                      const float* __restrict__ g1, const float* __restrict__ beta1,
                                                      const float* __restrict__ g2,
                                                      float* __restrict__ stats,
                                                      float* __restrict__ out) {
    __shared__ u16   f1t[4][16 * 64];
    __shared__ float smax[32][129];
    __shared__ float red[2][4][128];
    __shared__ float adt2s[64], adt3s[64], psign[128];
    __shared__ float adt0s[64], adt1s[64], ngs[64];
    const int t = threadIdx.x, lane = t & 63, w = t >> 6;
    const int cb = lane & 15, kq = lane >> 4;
    if (t < 64) {
        float mu1 = stats[128 + t] * INV_S, vr1 = stats[192 + t] * INV_S - mu1 * mu1;
        float a1 = rsqrtf(vr1 + EPS_) * g1[t];
        adt2s[t] = a1; adt3s[t] = beta1[t] - mu1 * a1;
        float mu0 = stats[t] * INV_S, vr0 = stats[64 + t] * INV_S - mu0 * mu0;
        float a0 = rsqrtf(vr0 + EPS_) * g0[t];
        adt0s[t] = a0; adt1s[t] = beta0[t] - mu0 * a0; ngs[t] = neg2[t];
    }
    if (t < 128) psign[t] = (g2[t] >= 0.f) ? 1.f : -1.f;
    __syncthreads();

    const int b = blockIdx.y;
    const int slb = blockIdx.x * 192 + w * 48;
    const uint4* w1p = (const uint4*)(pack + 8192);
    const uint4* w2p = (const uint4*)(pack + 12288);

    bf16x8 bf2[8][2];
    #pragma unroll
    for (int u = 0; u < 8; ++u)
        #pragma unroll
        for (int kk = 0; kk < 2; ++kk)
            bf2[u][kk] = __builtin_bit_cast(bf16x8, w2p[(u * 2 + kk) * 64 + lane]);

    float a1c[4], d1c[4];
    #pragma unroll
    for (int ct = 0; ct < 4; ++ct) { a1c[ct] = adt2s[ct * 16 + cb]; d1c[ct] = adt3s[ct * 16 + cb]; }

    float pmax_[2][4][2];
    #pragma unroll
    for (int h = 0; h < 2; ++h)
        #pragma unroll
        for (int ct = 0; ct < 4; ++ct) { pmax_[h][ct][0] = -3.402823466e+38f; pmax_[h][ct][1] = -3.402823466e+38f; }
    float ssum[8] = {0,0,0,0,0,0,0,0}, ssq[8] = {0,0,0,0,0,0,0,0};
    u16* fb = f1t[w];

    #pragma unroll
    for (int mt = 0; mt < 3; ++mt) {
        bf16x8 bf1[4][2];
        #pragma unroll
        for (int ct = 0; ct < 4; ++ct)
            #pragma unroll
            for (int kk = 0; kk < 2; ++kk)
                bf1[ct][kk] = __builtin_bit_cast(bf16x8, w1p[(ct * 2 + kk) * 64 + lane]);
        int sl = slb + sigma_sl(mt, cb);
        int n = sl / 6;
        int m = nidx[sl];
        int row1 = b * N_ + n;
        int row2 = (m < N_) ? (b * N_ + m) : -1;
        bf16x8 af[2];
        #pragma unroll
        for (int kk = 0; kk < 2; ++kk)
            af[kk] = build_af(V, row1, row2, adt0s, adt1s, ngs, kk * 32 + kq * 8);
        f32x4 z1v[4];
        #pragma unroll
        for (int ct = 0; ct < 4; ++ct) {
            f32x4 a = {};
            a = __builtin_amdgcn_mfma_f32_16x16x32_bf16(af[0], bf1[ct][0], a, 0, 0, 0);
            a = __builtin_amdgcn_mfma_f32_16x16x32_bf16(af[1], bf1[ct][1], a, 0, 0, 0);
            z1v[ct] = a;
        }
        #pragma unroll
        for (int ct = 0; ct < 4; ++ct)
            #pragma unroll
            for (int r = 0; r < 4; ++r) {
                float f1 = fmaxf(z1v[ct][r] * a1c[ct] + d1c[ct], 0.f);
                int rw = kq * 4 + r;
                fb[rw * 64 + ((ct * 16 + cb) ^ ((rw & 7) << 3))] = f2b(f1);
            }
        bf16x8 af2[2];
        #pragma unroll
        for (int kk = 0; kk < 2; ++kk) {
            int j0 = kk * 32 + kq * 8;
            af2[kk] = __builtin_bit_cast(bf16x8, *(const uint4*)(fb + cb * 64 + (j0 ^ ((cb & 7) << 3))));
        }
        #pragma unroll
        for (int half = 0; half < 2; ++half) {
            f32x4 acc2[4] = {};
            #pragma unroll
            for (int ct = 0; ct < 4; ++ct) {
                acc2[ct] = __builtin_amdgcn_mfma_f32_16x16x32_bf16(af2[0], bf2[half * 4 + ct][0], acc2[ct], 0, 0, 0);
                acc2[ct] = __builtin_amdgcn_mfma_f32_16x16x32_bf16(af2[1], bf2[half * 4 + ct][1], acc2[ct], 0, 0, 0);
            }
            #pragma unroll
            for (int ct = 0; ct < 4; ++ct) {
                float ps = psign[half * 64 + ct * 16 + cb];
                #pragma unroll
                for (int r = 0; r < 4; ++r) {
                    float z = acc2[ct][r];
                    ssum[half * 4 + ct] += z;
                    ssq[half * 4 + ct] = fmaf(z, z, ssq[half * 4 + ct]);
                    float zz = z * ps;
                    int pi = (mt == 0) ? 0 : ((mt == 2) ? 1 : ((r >= 2) ? 1 : 0));
                    pmax_[half][ct][pi] = fmaxf(pmax_[half][ct][pi], zz);
                }
            }
        }
    }
    #pragma unroll
    for (int half = 0; half < 2; ++half)
        #pragma unroll
        for (int ct = 0; ct < 4; ++ct)
            #pragma unroll
            for (int p = 0; p < 2; ++p)
                smax[w * 8 + kq * 2 + p][half * 64 + ct * 16 + cb] = pmax_[half][ct][p];
    #pragma unroll
    for (int j = 0; j < 8; ++j) {
        ssum[j] += __shfl_xor(ssum[j], 16); ssum[j] += __shfl_xor(ssum[j], 32);
        ssq[j]  += __shfl_xor(ssq[j], 16);  ssq[j]  += __shfl_xor(ssq[j], 32);
    }
    if (lane < 16) {
        #pragma unroll
        for (int j = 0; j < 8; ++j) {
            int c = (j >> 2) * 64 + (j & 3) * 16 + lane;
            red[0][w][c] = ssum[j];
            red[1][w][c] = ssq[j];
        }
    }
    __syncthreads();
    if (t < 128) {
        float s = (red[0][0][t] + red[0][1][t]) + (red[0][2][t] + red[0][3][t]);
        float q = (red[1][0][t] + red[1][1][t]) + (red[1][2][t] + red[1][3][t]);
        atomicAdd(&stats[256 + t], s);
        atomicAdd(&stats[384 + t], q);
    }
    {
        int c2 = t >> 1, nh = t & 1;
        float ps = psign[c2];
        float* op = out + OF_ + ((size_t)b * 128 + c2) * N_ + blockIdx.x * 32 + nh * 16;
        #pragma unroll
        for (int i4 = 0; i4 < 4; ++i4) {
            float4 v;
            v.x = smax[nh * 16 + i4 * 4 + 0][c2] * ps;
            v.y = smax[nh * 16 + i4 * 4 + 1][c2] * ps;
            v.z = smax[nh * 16 + i4 * 4 + 2][c2] * ps;
            v.w = smax[nh * 16 + i4 * 4 + 3][c2] * ps;
            *(float4*)(op + i4 * 4) = v;
        }
    }
}

// ---------------- P4 big: read bf16 raw, normalize -> out, fused channel max ----------------
__global__ __launch_bounds__(256) void p4big_kernel(const float* __restrict__ g2,
                                                    const float* __restrict__ beta2,
                                                    const float* __restrict__ stats,
                                                    const u16* __restrict__ raw,
                                                    float* __restrict__ out) {
    __shared__ float a2s[128], d2s[128];
    __shared__ float vred[4][64];
    const int t = threadIdx.x, lane = t & 63, cg = t >> 6;
    if (t < 128) {
        float mu = stats[256 + t] * INV_S;
        float vr = stats[384 + t] * INV_S - mu * mu;
        float a = rsqrtf(vr + EPS_) * g2[t];
        a2s[t] = a;
        d2s[t] = beta2[t] - mu * a;
    }
    __syncthreads();
    const int b = blockIdx.y;
    const int n = blockIdx.x * 64 + lane;
    const u16* rp = raw + ((size_t)b * 128 + cg * 32) * N_ + n;
    float* op = out + OF_ + ((size_t)b * 128 + cg * 32) * N_ + n;
    float vmax = -3.402823466e+38f;
    #pragma unroll 8
    for (int c = 0; c < 32; ++c) {
        int c2 = cg * 32 + c;
        float v = fmaxf(b2fu(rp[(size_t)c * N_]) * a2s[c2] + d2s[c2], 0.f);
        op[(size_t)c * N_] = v;
        vmax = fmaxf(vmax, v);
    }
    vred[cg][lane] = vmax;
    __syncthreads();
    if (t < 64)
        out[b * N_ + blockIdx.x * 64 + t] =
            fmaxf(fmaxf(vred[0][t], vred[1][t]), fmaxf(vred[2][t], vred[3][t]));
}

// ---------------- P4 small (round-6 logic) ----------------
__global__ __launch_bounds__(256) void p4small_kernel(const float* __restrict__ g2,
                                                      const float* __restrict__ beta2,
                                                      const float* __restrict__ stats,
                                                      float* __restrict__ outbuf) {
    __shared__ float a2s[128], d2s[128];
    const int t = threadIdx.x;
    if (t < 128) {
        float mu = stats[256 + t] * INV_S;
        float vr = stats[384 + t] * INV_S - mu * mu;
        float a = rsqrtf(vr + EPS_) * g2[t];
        a2s[t] = a;
        d2s[t] = beta2[t] - mu * a;
    }
    __syncthreads();
    const int b = blockIdx.y;
    const int n = blockIdx.x * 256 + t;
    if (n >= N_) return;
    float vmax = -3.402823466e+38f;
    #pragma unroll 8
    for (int c2 = 0; c2 < 128; ++c2) {
        size_t idx = OF_ + ((size_t)b * 128 + c2) * N_ + n;
        float v = fmaxf(outbuf[idx] * a2s[c2] + d2s[c2], 0.f);
        outbuf[idx] = v;
        vmax = fmaxf(vmax, v);
    }
    outbuf[b * N_ + n] = vmax;
}

extern "C" void kernel_launch(void* const* d_in, const int* in_sizes, int n_in,
                              void* d_out, int out_size, void* d_ws, size_t ws_size,
                              hipStream_t stream) {
    (void)in_sizes; (void)n_in; (void)out_size;
    const float* pts   = (const float*)d_in[0];
    const int*   nidx  = (const int*)d_in[1];
    const float* W0    = (const float*)d_in[2];
    const float* g0    = (const float*)d_in[4];
    const float* beta0 = (const float*)d_in[5];
    const float* W1    = (const float*)d_in[6];
    const float* g1    = (const float*)d_in[8];
    const float* beta1 = (const float*)d_in[9];
    const float* W2    = (const float*)d_in[10];
    const float* g2    = (const float*)d_in[12];
    const float* beta2 = (const float*)d_in[13];
    const bool big = ws_size >= NEED_BIG_B;
    u16*   V     = (u16*)d_ws;                 // doubles as bf16 raw-max buffer in big path
    u16*   z1b   = big ? ((u16*)d_ws + WS_V_U16) : nullptr;
    float* stats = (float*)d_ws + (big ? 20480000 : 5120000);
    float* neg2  = stats + 512;
    u16*   pack  = (u16*)d_ws + (big ? 40961152 : 10241152);
    float* out   = (float*)d_out;

    hipLaunchKernelGGL(wprep_kernel, dim3(1), dim3(256), 0, stream, W0, W1, W2, stats, neg2, pack);
    hipLaunchKernelGGL(p0_kernel, dim3((N_ + 191) / 192, B_), dim3(256), 0, stream, pts, pack, V);
    hipLaunchKernelGGL(p1_kernel, dim3(SPB / 384, B_), dim3(256), 0, stream, V, nidx, neg2, stats);
    if (big) {
        hipLaunchKernelGGL((p2_kernel<1>), dim3(SPB / 192, B_), dim3(256), 0, stream,
                           V, nidx, neg2, pack, g0, beta0, stats, z1b);
        hipLaunchKernelGGL(p3big_kernel, dim3(TILES_PB / 4, B_), dim3(256), 0, stream,
                           z1b, pack, g1, beta1, g2, stats, V);
        hipLaunchKernelGGL(p4big_kernel, dim3(N_ / 64, B_), dim3(256), 0, stream,
                           g2, beta2, stats, V, out);
    } else {
        hipLaunchKernelGGL((p2_kernel<0>), dim3(SPB / 192, B_), dim3(256), 0, stream,
                           V, nidx, neg2, pack, g0, beta0, stats, nullptr);
        hipLaunchKernelGGL(p3small_kernel, dim3(SPB / 192, B_), dim3(256), 0, stream,
                           V, nidx, neg2, pack, g0, beta0, g1, beta1, g2, stats, out);
        hipLaunchKernelGGL(p4small_kernel, dim3((N_ + 255) / 256, B_), dim3(256), 0, stream,
                           g2, beta2, stats, out);
    }
}